// Round 9
// baseline (784.861 us; speedup 1.0000x reference)
//
#include <hip/hip_runtime.h>
#include <math.h>

#define N_NODES 30000
#define N_EDGES 480000
#define HDIM 128
#define EPB 64        // nodes per node-kernel block
#define EB 32         // edges per edge/coord block (128 threads); any node
                      // degree is handled via multi-block headp continuation.
#define NAS 264       // node A-tile row stride (bf16)
#define MS 136        // m1 / Ht row stride (bf16)
#define M2TS 36       // transposed m2 row stride (bf16): [128 cols][36]

typedef __attribute__((ext_vector_type(8))) short short8b;
typedef __attribute__((ext_vector_type(4))) float f32x4;

__device__ __forceinline__ float silu_f(float v) {
  return v / (1.0f + __expf(-v));
}

__device__ __forceinline__ unsigned short f2bf(float f) {
  unsigned int u = __float_as_uint(f);
  unsigned int r = u + 0x7fffu + ((u >> 16) & 1u);
  return (unsigned short)(r >> 16);
}

// HW packed f32->bf16 (RNE, same rounding as f2bf): 1 instr replaces ~9.
__device__ __forceinline__ unsigned int cvt_pk_bf16(float lo, float hi) {
  unsigned int r;
  asm("v_cvt_pk_bf16_f32 %0, %1, %2" : "=v"(r) : "v"(lo), "v"(hi));
  return r;
}

__device__ __forceinline__ ushort4 pk4(float4 v) {
  uint2 u;
  u.x = cvt_pk_bf16(v.x, v.y);
  u.y = cvt_pk_bf16(v.z, v.w);
  return *(ushort4*)&u;
}

// ---- fused init: out = [h | x], edge count histogram ------
__global__ void init_out_bf_kernel(const float* __restrict__ h,
                                   const float* __restrict__ x,
                                   const int* __restrict__ ei,
                                   float* __restrict__ out,
                                   int* __restrict__ cursor) {
  int idx = blockIdx.x * 256 + threadIdx.x;   // 960,000 float4 units
  ((float4*)out)[idx] = ((const float4*)h)[idx];
  if (idx < N_NODES * 3 / 4) {
    ((float4*)(out + N_NODES * HDIM))[idx] = ((const float4*)x)[idx];
  }
  if (idx < N_EDGES) atomicAdd(&cursor[ei[idx]], 1);
}

__global__ __launch_bounds__(1024) void scan_kernel(int* __restrict__ cursor,
                                                    int* __restrict__ cstart) {
  __shared__ int sums[1024];
  const int tid = threadIdx.x;
  const int base = tid * 30;
  int local[30];
  int s = 0;
#pragma unroll
  for (int j = 0; j < 30; ++j) {
    int idx = base + j;
    int d = (idx < N_NODES) ? cursor[idx] : 0;
    local[j] = s;
    s += d;
  }
  sums[tid] = s;
  __syncthreads();
  for (int off = 1; off < 1024; off <<= 1) {
    int add = (tid >= off) ? sums[tid - off] : 0;
    __syncthreads();
    sums[tid] += add;
    __syncthreads();
  }
  int excl = (tid == 0) ? 0 : sums[tid - 1];
#pragma unroll
  for (int j = 0; j < 30; ++j) {
    int idx = base + j;
    if (idx < N_NODES) {
      int v = excl + local[j];
      cursor[idx] = v;
      cstart[idx] = v;   // immutable CSR starts (cursor mutates in fill)
    }
  }
}

// ---- merged post-scan prep: fill | weight-convert | ns_init | gk | l0-P ---
// block ranges: 0-1874 fill (writes sorted rcp/era), 1875-2754 convert
// (55 chunks), 2755-3010 ns_init, 3011-3266 gk, 3267-3735 pgemm for layer 0.
__global__ void prep_kernel(
    const int* __restrict__ ei, int* __restrict__ cursor,
    unsigned int* __restrict__ rcp, float2* __restrict__ era,
    const float* __restrict__ x, const float* __restrict__ ea,
    const float* __restrict__ e_w1, const float* __restrict__ e_w2,
    const float* __restrict__ enc_w, const float* __restrict__ c_w1,
    const float* __restrict__ c_w2,
    ushort* __restrict__ w1cs, ushort* __restrict__ w2cs,
    ushort* __restrict__ enccs, ushort* __restrict__ cw1cs,
    ushort* __restrict__ cw2cs,
    const float* __restrict__ A_re, const float* __restrict__ A_im,
    float2* __restrict__ X,
    const float* __restrict__ coeffs, float2* __restrict__ gkm,
    const float* __restrict__ outh, const float* __restrict__ b1l0,
    ushort* __restrict__ P) {
  __shared__ ushort Ht[EPB * MS];   // used by the pgemm range only
  const int b = blockIdx.x, tid = threadIdx.x;
  if (b < 1875) {
    int e = b * 256 + tid;
    int r = ei[e];
    int c = ei[N_EDGES + e];
    int pos = atomicAdd(&cursor[r], 1);   // after: cursor[n] = CSR end
    rcp[pos] = (unsigned int)r | ((unsigned int)c << 16);
    float dx = x[r * 3 + 0] - x[c * 3 + 0];
    float dy = x[r * 3 + 1] - x[c * 3 + 1];
    float dz = x[r * 3 + 2] - x[c * 3 + 2];
    era[pos] = make_float2(dx * dx + dy * dy + dz * dz, ea[e]);
  } else if (b < 2755) {
    int idx = (b - 1875) * 256 + tid;     // 0 .. 225279 (= 55*4096)
    int ci = idx >> 12, rem = idx & 4095, kk = rem & 31;
    const float* W; ushort* dst; int Kreal, ktl;
    if (ci < 18) {
      int l = ci / 9; ktl = ci - l * 9;
      W = e_w1 + (size_t)l * 258 * HDIM; dst = w1cs + (size_t)l * 9 * 4096;
      Kreal = 258;
    } else if (ci < 26) {
      int c2 = ci - 18; int l = c2 >> 2; ktl = c2 & 3;
      W = e_w2 + (size_t)l * HDIM * HDIM; dst = w2cs + (size_t)l * 4 * 4096;
      Kreal = 128;
    } else if (ci < 42) {
      int c2 = ci - 26; int l = c2 >> 3; ktl = c2 & 7;
      W = enc_w + (size_t)l * 256 * HDIM; dst = enccs + (size_t)l * 8 * 4096;
      Kreal = 256;
    } else if (ci < 51) {
      ktl = ci - 42; W = c_w1; dst = cw1cs; Kreal = 258;
    } else {
      ktl = ci - 51; W = c_w2; dst = cw2cs; Kreal = 128;
    }
    int n = rem >> 5;
    int k = ktl * 32 + kk;
    float v = (k < Kreal) ? W[(size_t)k * HDIM + n] : 0.0f;
    dst[ktl * 4096 + rem] = f2bf(v);
  } else if (b < 3011) {
    int bb = b - 2755;
    int lj = bb >> 6;
    int idx = (bb & 63) * 256 + tid;
    int r = idx >> 7, c = idx & 127;
    const float* are = A_re + (size_t)lj * 16384;
    const float* aim = A_im + (size_t)lj * 16384;
    float re = are[r * 128 + c] + are[c * 128 + r];
    float im = aim[r * 128 + c] - aim[c * 128 + r];
    if (r == c) im -= 1.0f;
    X[(size_t)lj * 16384 + idx] = make_float2(re, im);
  } else if (b < 3267) {
    int bb = b - 3011;
    int lj = bb >> 6;
    float a = coeffs[lj * 2 + 0], bcf = coeffs[lj * 2 + 1];
    float ca = cosf(0.5f * a), sa = sinf(0.5f * a);
    float cb = cosf(0.5f * bcf), sb = sinf(0.5f * bcf);
    float2 G[2][2];
    G[0][0] = make_float2(cb * ca, sb * sa);
    G[0][1] = make_float2(-sb * ca, -cb * sa);
    G[1][0] = make_float2(sb * ca, -cb * sa);
    G[1][1] = make_float2(cb * ca, -sb * sa);
    int idx = (bb & 63) * 256 + tid;
    int r = idx >> 7, c = idx & 127;
    float2 acc = make_float2(1.f, 0.f);
#pragma unroll
    for (int bit = 6; bit >= 0; --bit) {
      float2 g = G[(r >> bit) & 1][(c >> bit) & 1];
      acc = make_float2(acc.x * g.x - acc.y * g.y, acc.x * g.y + acc.y * g.x);
    }
    gkm[(size_t)lj * 16384 + idx] = acc;
  } else {
    // ---- pgemm for layer 0: P = [h@W1r + b1 | h@W1c], staged from out ----
    const int n0 = (b - 3267) * EPB;
    const int lane = tid & 63, wave = tid >> 6;
    const int lrow = lane & 15, lq = lane >> 4;
    {
      const int e = tid >> 2, jj = tid & 3;
      int node = n0 + e;
      if (node >= N_NODES) node = N_NODES - 1;
      const float4* s4 = (const float4*)(outh + (size_t)node * HDIM + jj * 32);
      ushort* dst = Ht + e * MS + jj * 32;
#pragma unroll
      for (int i = 0; i < 8; ++i) {
        ((ushort4*)dst)[i] = pk4(s4[i]);
      }
    }
    short8b wf[4][4];
    const int cs = (wave >> 1) * 4;     // waves 0,1 -> W1r; 2,3 -> W1c
    const int nb = (wave & 1) * 64;
#pragma unroll
    for (int kt = 0; kt < 4; ++kt)
#pragma unroll
      for (int nt = 0; nt < 4; ++nt)
        wf[kt][nt] = *(const short8b*)(w1cs + (cs + kt) * 4096 + (nb + nt * 16 + lrow) * 32 + lq * 8);
    __syncthreads();

    f32x4 acc[4][4];
#pragma unroll
    for (int mt = 0; mt < 4; ++mt)
#pragma unroll
      for (int nt = 0; nt < 4; ++nt) acc[mt][nt] = (f32x4){0.f, 0.f, 0.f, 0.f};
#pragma unroll
    for (int kt = 0; kt < 4; ++kt) {
      short8b af[4];
#pragma unroll
      for (int mt = 0; mt < 4; ++mt)
        af[mt] = *(const short8b*)(Ht + (mt * 16 + lrow) * MS + kt * 32 + lq * 8);
#pragma unroll
      for (int mt = 0; mt < 4; ++mt)
#pragma unroll
        for (int nt = 0; nt < 4; ++nt)
          acc[mt][nt] = __builtin_amdgcn_mfma_f32_16x16x32_bf16(af[mt], wf[kt][nt], acc[mt][nt], 0, 0, 0);
    }
    const int cbase = wave * 64;
#pragma unroll
    for (int nt = 0; nt < 4; ++nt) {
      const int ccol = cbase + nt * 16 + lrow;
      const float bb2 = (ccol < 128) ? b1l0[ccol] : 0.f;
#pragma unroll
      for (int mt = 0; mt < 4; ++mt)
#pragma unroll
        for (int r = 0; r < 4; ++r) {
          const int node = n0 + mt * 16 + lq * 4 + r;
          if (node < N_NODES) P[(size_t)node * 256 + ccol] = f2bf(acc[mt][nt][r] + bb2);
        }
    }
  }
}

// ============ Newton-Schulz inverse of B = A_h + iI (2 iterations) ========
__global__ void ns_bx_kernel(const float* __restrict__ Are,
                             const float* __restrict__ Aim,
                             const float2* __restrict__ X,
                             float2* __restrict__ T) {
  int lj = blockIdx.y;
  int idx = blockIdx.x * 256 + threadIdx.x;
  int r = idx >> 7, c = idx & 127;
  const float* are = Are + (size_t)lj * 16384;
  const float* aim = Aim + (size_t)lj * 16384;
  const float2* x = X + (size_t)lj * 16384;
  float2 acc = make_float2(0.f, 0.f);
  for (int k = 0; k < 128; ++k) {
    float re = are[r * 128 + k] + are[k * 128 + r];
    float im = aim[r * 128 + k] - aim[k * 128 + r];
    if (k == r) im += 1.0f;
    float2 b = x[k * 128 + c];
    acc.x += re * b.x - im * b.y;
    acc.y += re * b.y + im * b.x;
  }
  T[(size_t)lj * 16384 + idx] = acc;
}

__global__ void ns_upd_kernel(const float2* __restrict__ X,
                              const float2* __restrict__ T,
                              float2* __restrict__ Xn) {
  int lj = blockIdx.y;
  int idx = blockIdx.x * 256 + threadIdx.x;
  int r = idx >> 7, c = idx & 127;
  const float2* x = X + (size_t)lj * 16384;
  const float2* t = T + (size_t)lj * 16384;
  float2 acc = make_float2(0.f, 0.f);
  for (int k = 0; k < 128; ++k) {
    float2 a = x[r * 128 + k];
    float2 b = t[k * 128 + c];
    acc.x += a.x * b.x - a.y * b.y;
    acc.y += a.x * b.y + a.y * b.x;
  }
  float2 xc = x[r * 128 + c];
  Xn[(size_t)lj * 16384 + idx] = make_float2(2.f * xc.x - acc.x, 2.f * xc.y - acc.y);
}

// ---------------- q = (A_h - iI) * Binv ----------------
__global__ void qmat_kernel(const float* __restrict__ Are,
                            const float* __restrict__ Aim,
                            const float2* __restrict__ binvg,
                            float2* __restrict__ qm) {
  int lj = blockIdx.y;
  int idx = blockIdx.x * 256 + threadIdx.x;
  int r = idx >> 7, c = idx & 127;
  const float* are = Are + (size_t)lj * 16384;
  const float* aim = Aim + (size_t)lj * 16384;
  const float2* binv = binvg + (size_t)lj * 16384;
  float2 acc = make_float2(0.f, 0.f);
  for (int k = 0; k < 128; ++k) {
    float re = are[r * 128 + k] + are[k * 128 + r];
    float im = aim[r * 128 + k] - aim[k * 128 + r];
    if (k == r) im -= 1.0f;
    float2 b = binv[k * 128 + c];
    acc.x += re * b.x - im * b.y;
    acc.y += re * b.y + im * b.x;
  }
  qm[(size_t)lj * 16384 + idx] = acc;
}

// ------- N_j[i][c] = sum_k q[k][i] * Gk[g[c]][k]  (CNOT perm inlined) ------
__global__ void nj_kernel(const float2* __restrict__ qm,
                          const float2* __restrict__ gkm,
                          float2* __restrict__ njm) {
  int lj = blockIdx.y;
  int idx = blockIdx.x * 256 + threadIdx.x;
  int i = idx >> 7, c = idx & 127;
  int gc;
  {
    int v = c;
    const int cs[7] = {6, 5, 4, 3, 2, 1, 0};
    const int ts[7] = {0, 6, 5, 4, 3, 2, 1};
#pragma unroll
    for (int p = 0; p < 7; ++p) {
      int cb = (v >> (6 - cs[p])) & 1;
      v = v ^ (cb << (6 - ts[p]));
    }
    gc = v;
  }
  const float2* q = qm + (size_t)lj * 16384;
  const float2* gk = gkm + (size_t)lj * 16384;
  float2 acc = make_float2(0.f, 0.f);
  for (int k = 0; k < 128; ++k) {
    float2 qa = q[k * 128 + i];
    float2 gb = gk[gc * 128 + k];
    acc.x += qa.x * gb.x - qa.y * gb.y;
    acc.y += qa.x * gb.y + qa.y * gb.x;
  }
  njm[(size_t)lj * 16384 + idx] = acc;
}

// ---------------- U_l = N_{l,0} @ N_{l,1} ----------------
__global__ void compose_kernel(const float2* __restrict__ njm,
                               float2* __restrict__ um) {
  int l = blockIdx.y;
  int idx = blockIdx.x * 256 + threadIdx.x;
  int i = idx >> 7, c = idx & 127;
  const float2* n0 = njm + (size_t)(l * 2 + 0) * 16384;
  const float2* n1 = njm + (size_t)(l * 2 + 1) * 16384;
  float2 acc = make_float2(0.f, 0.f);
  for (int k = 0; k < 128; ++k) {
    float2 a = n0[i * 128 + k];
    float2 b = n1[k * 128 + c];
    acc.x += a.x * b.x - a.y * b.y;
    acc.y += a.x * b.y + a.y * b.x;
  }
  um[(size_t)l * 16384 + idx] = acc;
}

// -------- Wqd_l = Re(U_l) @ dec_w_l, written DIRECTLY as bf16 chunks -------
__global__ void wqd_kernel(const float2* __restrict__ um,
                           const float* __restrict__ decw,
                           ushort* __restrict__ wqdcs) {
  int l = blockIdx.y;
  int idx = blockIdx.x * 256 + threadIdx.x;
  int i = idx >> 7, c = idx & 127;     // i = k-dim (D), c = n-dim (H)
  const float2* u = um + (size_t)l * 16384;
  const float* dw = decw + (size_t)l * 16384;
  float acc = 0.f;
  for (int k = 0; k < 128; ++k) acc += u[i * 128 + k].x * dw[k * 128 + c];
  wqdcs[(size_t)l * 4 * 4096 + (i >> 5) * 4096 + c * 32 + (i & 31)] = f2bf(acc);
}

// ==================== edge MLP: EB=32, 128-thread blocks ===================
// Round-9: small blocks for occupancy/phase-overlap. 16 workgroups/CU
// (9.6KB LDS each) = 32 waves resident; barriers sync only 2 waves, so
// independent blocks cover each other's gather/barrier stalls. Indicator
// GEMM becomes K=32 (single B-frag, 4 MFMAs/wave). Multi-block node spans
// handled by the generalized headp continuation (middle blocks write their
// own headp slot; node folds (s>>5)+1 .. (en-1)>>5).
__global__ __launch_bounds__(128, 8) void edge_mfma_kernel(
    const ushort* __restrict__ P, const unsigned int* __restrict__ rcp,
    const float2* __restrict__ era, const int* __restrict__ cstart,
    const float* __restrict__ wm,      // f32: [0:128]=radial row, [128:256]=ea row
    const ushort* __restrict__ w2cs, const float* __restrict__ b2,
    float* __restrict__ agg, float* __restrict__ headp) {
  __shared__ ushort buf[128 * M2TS];     // m1 (32x136=4352 us) / m2t (4608 us)
  __shared__ int rows[EB];
  __shared__ __align__(16) ushort segv[EB];
  __shared__ int segnode[EB];
  __shared__ int scont, snseg;
  ushort* m1 = buf;
  ushort* m2t = buf;

  const int tid = threadIdx.x;
  const int lane = tid & 63, wave = tid >> 6;
  const int lrow = lane & 15, lq = lane >> 4;
  const int cb = wave * 64;              // this wave's 64 output cols
  const float b2v[4] = {b2[cb + lrow], b2[cb + 16 + lrow],
                        b2[cb + 32 + lrow], b2[cb + 48 + lrow]};

  const int i0 = blockIdx.x * EB;
  {
    const int e = tid >> 2, j = tid & 3;
    const unsigned int rcv = rcp[i0 + e];
    const int r = (int)(rcv & 0xFFFFu), c = (int)(rcv >> 16);
    if (j == 0) rows[e] = r;
    const float2 re2 = era[i0 + e];
    const float radial = re2.x, eav = re2.y;
    const uint4* pr = (const uint4*)(P + (size_t)r * 256 + j * 32);
    const uint4* pc = (const uint4*)(P + (size_t)c * 256 + 128 + j * 32);
    uint4 PR[4] = {pr[0], pr[1], pr[2], pr[3]};
    uint4 PC[4] = {pc[0], pc[1], pc[2], pc[3]};
#pragma unroll
    for (int q = 0; q < 4; ++q) {
      const int kb = j * 32 + q * 8;
      const uint ua[4] = {PR[q].x, PR[q].y, PR[q].z, PR[q].w};
      const uint ub[4] = {PC[q].x, PC[q].y, PC[q].z, PC[q].w};
      uint ow[4];
#pragma unroll
      for (int w = 0; w < 4; ++w) {
        const int k = kb + w * 2;
        float v0 = __uint_as_float(ua[w] << 16) + __uint_as_float(ub[w] << 16)
                 + radial * wm[k] + eav * wm[128 + k];
        float v1 = __uint_as_float(ua[w] & 0xffff0000u) + __uint_as_float(ub[w] & 0xffff0000u)
                 + radial * wm[k + 1] + eav * wm[129 + k];
        ow[w] = cvt_pk_bf16(silu_f(v0), silu_f(v1));
      }
      uint4 o; o.x = ow[0]; o.y = ow[1]; o.z = ow[2]; o.w = ow[3];
      *(uint4*)(m1 + e * MS + kb) = o;
    }
  }
  __syncthreads();   // s1: m1 ready

  // ---- GEMM2: 2 edge-tiles x 4 col-tiles per wave ----
  f32x4 acc2[2][4];
#pragma unroll
  for (int mt = 0; mt < 2; ++mt)
#pragma unroll
    for (int nt = 0; nt < 4; ++nt) acc2[mt][nt] = (f32x4){0.f, 0.f, 0.f, 0.f};
#pragma unroll
  for (int kt = 0; kt < 4; ++kt) {
    short8b wf[4];
#pragma unroll
    for (int nt = 0; nt < 4; ++nt)
      wf[nt] = *(const short8b*)(w2cs + kt * 4096 + (cb + nt * 16 + lrow) * 32 + lq * 8);
    short8b af[2];
#pragma unroll
    for (int mt = 0; mt < 2; ++mt)
      af[mt] = *(const short8b*)(m1 + (mt * 16 + lrow) * MS + kt * 32 + lq * 8);
#pragma unroll
    for (int mt = 0; mt < 2; ++mt)
#pragma unroll
      for (int nt = 0; nt < 4; ++nt)
        acc2[mt][nt] = __builtin_amdgcn_mfma_f32_16x16x32_bf16(af[mt], wf[nt], acc2[mt][nt], 0, 0, 0);
  }
  __syncthreads();   // s2: all m1 reads done (m2t overlays)

  // m2 (bf16, transposed [col][edge]) written packed (cvt_pk + b64 store);
  // each wave writes ALL 32 edges of its own 64 cols.
#pragma unroll
  for (int mt = 0; mt < 2; ++mt)
#pragma unroll
    for (int nt = 0; nt < 4; ++nt) {
      const int col = cb + nt * 16 + lrow;
      uint2 u;
      u.x = cvt_pk_bf16(silu_f(acc2[mt][nt][0] + b2v[nt]),
                        silu_f(acc2[mt][nt][1] + b2v[nt]));
      u.y = cvt_pk_bf16(silu_f(acc2[mt][nt][2] + b2v[nt]),
                        silu_f(acc2[mt][nt][3] + b2v[nt]));
      *(uint2*)(m2t + col * M2TS + mt * 16 + lq * 4) = u;
    }
  if (wave == 0) {
    const int e = lane;
    const bool valid = e < EB;
    const int re_ = rows[valid ? e : (EB - 1)];
    const bool leader = valid && (e == 0 || rows[e - 1] != re_);
    const unsigned long long mask = __ballot(leader);
    if (valid) {
      const int seg = (int)__popcll(mask & ((1ull << e) - 1ull));
      segv[e] = (ushort)seg;
      if (leader) segnode[seg] = re_;
    }
    if (e == 0) {
      snseg = (int)__popcll(mask);
      scont = (cstart[re_] < i0) ? 1 : 0;
    }
  }
  __syncthreads();   // s3: m2t + seg ready

  // indicator GEMM (K=32): OUT[m2col][seg] = sum_e m2t[col][e]*(segv[e]==seg)
  const int nseg = snseg, cont = scont;
  const int ntmax = (nseg + 15) >> 4;     // usually 1
  const short8b sv = *(const short8b*)(segv + lq * 8);
  short8b afr[4];
#pragma unroll
  for (int mi = 0; mi < 4; ++mi)
    afr[mi] = *(const short8b*)(m2t + (cb + mi * 16 + lrow) * M2TS + lq * 8);
  for (int nt = 0; nt < ntmax; ++nt) {    // block-uniform
    const int tgt = nt * 16 + lrow;
    uint p[4];
#pragma unroll
    for (int w = 0; w < 4; ++w) {
      p[w] = (((int)(ushort)sv[2 * w] == tgt) ? 0x3F80u : 0u)
           | (((int)(ushort)sv[2 * w + 1] == tgt) ? 0x3F800000u : 0u);
    }
    uint4 u0 = make_uint4(p[0], p[1], p[2], p[3]);
    const short8b bf = *(const short8b*)&u0;
    f32x4 racc[4];
#pragma unroll
    for (int mi = 0; mi < 4; ++mi) {
      racc[mi] = (f32x4){0.f, 0.f, 0.f, 0.f};
      racc[mi] = __builtin_amdgcn_mfma_f32_16x16x32_bf16(afr[mi], bf, racc[mi], 0, 0, 0);
    }
    const int seg = tgt;
    if (seg < nseg) {
      const int node = segnode[seg];
      float* dst = (seg == 0 && cont) ? (headp + (size_t)blockIdx.x * HDIM)
                                      : (agg + (size_t)node * HDIM);
#pragma unroll
      for (int mi = 0; mi < 4; ++mi)
#pragma unroll
        for (int r = 0; r < 4; ++r)
          dst[cb + mi * 16 + lq * 4 + r] = racc[mi][r];
    }
  }
}

// ==================== MFMA node update (folds headp, emits next-layer P) ===
__global__ __launch_bounds__(256, 2) void node_mfma_kernel(
    float* __restrict__ out_h, const float* __restrict__ agg,
    const int* __restrict__ cstart, const int* __restrict__ cend,
    const float* __restrict__ headp,
    const ushort* __restrict__ enccs, const float* __restrict__ encb,
    const ushort* __restrict__ wqdcs, const float* __restrict__ decb,
    const ushort* __restrict__ w1n, const float* __restrict__ b1n,
    ushort* __restrict__ Pout) {
  __shared__ ushort A[EPB * NAS];
  __shared__ ushort m1[EPB * MS];
  __shared__ float nbuf[4 * EPB];
  const int tid = threadIdx.x;
  const int n0 = blockIdx.x * EPB;

  const int lane = tid & 63, wave = tid >> 6;
  const int lrow = lane & 15, lq = lane >> 4;
  const int wbase = wave * 32;

  short8b wef[8][2], wqf[4][2];
#pragma unroll
  for (int kt = 0; kt < 8; ++kt)
#pragma unroll
    for (int nt = 0; nt < 2; ++nt)
      wef[kt][nt] = *(const short8b*)(enccs + kt * 4096 + (wbase + nt * 16 + lrow) * 32 + lq * 8);
#pragma unroll
  for (int kt = 0; kt < 4; ++kt)
#pragma unroll
    for (int nt = 0; nt < 2; ++nt)
      wqf[kt][nt] = *(const short8b*)(wqdcs + kt * 4096 + (wbase + nt * 16 + lrow) * 32 + lq * 8);
  const float ebv[2] = {encb[wbase + lrow], encb[wbase + 16 + lrow]};
  const float dbv[2] = {decb[wbase + lrow], decb[wbase + 16 + lrow]};

  {
    const int e = tid >> 2, j = tid & 3;
    int node = n0 + e;
    if (node >= N_NODES) node = N_NODES - 1;
    if (j < 2) {
      const float4* s4 = (const float4*)(out_h + (size_t)node * HDIM + j * 64);
      ushort* dst = A + e * NAS + j * 64;
#pragma unroll
      for (int i = 0; i < 16; ++i) {
        ((ushort4*)dst)[i] = pk4(s4[i]);
      }
    } else {
      const int s = cstart[node], en = cend[node];
      const bool hasAgg = en > s;
      const float4* a4 = (const float4*)(agg + (size_t)node * HDIM + (j - 2) * 64);
      const int bb0 = (s >> 5) + 1;            // EB=32 edge blocks
      const int bb1 = hasAgg ? ((en - 1) >> 5) : 0;
      ushort* dst = A + e * NAS + 128 + (j - 2) * 64;
#pragma unroll
      for (int i = 0; i < 16; ++i) {
        float4 v = hasAgg ? a4[i] : make_float4(0.f, 0.f, 0.f, 0.f);
        for (int bb = bb0; bb <= bb1; ++bb) {
          float4 hv = *(const float4*)(headp + (size_t)bb * HDIM + (j - 2) * 64 + i * 4);
          v.x += hv.x; v.y += hv.y; v.z += hv.z; v.w += hv.w;
        }
        float4 sv = make_float4(v.x * 0.01f, v.y * 0.01f, v.z * 0.01f, v.w * 0.01f);
        ((ushort4*)dst)[i] = pk4(sv);
      }
    }
  }
  __syncthreads();

  f32x4 acc[4][2];
#pragma unroll
  for (int mt = 0; mt < 4; ++mt)
#pragma unroll
    for (int nt = 0; nt < 2; ++nt) acc[mt][nt] = (f32x4){0.f, 0.f, 0.f, 0.f};
#pragma unroll
  for (int kt = 0; kt < 8; ++kt) {
    short8b af[4];
#pragma unroll
    for (int mt = 0; mt < 4; ++mt)
      af[mt] = *(const short8b*)(A + (mt * 16 + lrow) * NAS + kt * 32 + lq * 8);
#pragma unroll
    for (int mt = 0; mt < 4; ++mt)
#pragma unroll
      for (int nt = 0; nt < 2; ++nt)
        acc[mt][nt] = __builtin_amdgcn_mfma_f32_16x16x32_bf16(af[mt], wef[kt][nt], acc[mt][nt], 0, 0, 0);
  }
#pragma unroll
  for (int mt = 0; mt < 4; ++mt) {
    float ssp[4] = {0.f, 0.f, 0.f, 0.f};
#pragma unroll
    for (int nt = 0; nt < 2; ++nt)
#pragma unroll
      for (int r = 0; r < 4; ++r) {
        acc[mt][nt][r] += ebv[nt];
        ssp[r] += acc[mt][nt][r] * acc[mt][nt][r];
      }
#pragma unroll
    for (int m = 1; m < 16; m <<= 1)
#pragma unroll
      for (int r = 0; r < 4; ++r) ssp[r] += __shfl_xor(ssp[r], m, 64);
    if (lrow == 0) {
#pragma unroll
      for (int r = 0; r < 4; ++r)
        nbuf[wave * EPB + mt * 16 + lq * 4 + r] = ssp[r];
    }
  }
  __syncthreads();
#pragma unroll
  for (int mt = 0; mt < 4; ++mt)
#pragma unroll
    for (int r = 0; r < 4; ++r) {
      const int row = mt * 16 + lq * 4 + r;
      float sum = nbuf[row] + nbuf[EPB + row] + nbuf[2 * EPB + row] + nbuf[3 * EPB + row];
      float inv = 1.0f / sqrtf(sum + 1e-12f);
#pragma unroll
      for (int nt = 0; nt < 2; ++nt)
        m1[row * MS + wbase + nt * 16 + lrow] = f2bf(acc[mt][nt][r] * inv);
    }
  __syncthreads();

  f32x4 acc2[4][2];
#pragma unroll
  for (int mt = 0; mt < 4; ++mt)
#pragma unroll
    for (int nt = 0; nt < 2; ++nt) acc2[mt][nt] = (f32x4){0.f, 0.f, 0.f, 0.f};
#pragma unroll
  for (int kt = 0; kt < 4; ++kt) {
    short8b af[4];
#pragma unroll
    for (int mt = 0; mt < 4; ++mt)
      af[mt] = *(const short8b*)(m1 + (mt * 16 + lrow) * MS + kt * 32 + lq * 8);
#pragma unroll
    for (int mt = 0; mt < 4; ++mt)
#pragma unroll
      for (int nt = 0; nt < 2; ++nt)
        acc2[mt][nt] = __builtin_amdgcn_mfma_f32_16x16x32_bf16(af[mt], wqf[kt][nt], acc2[mt][nt], 0, 0, 0);
  }
  __syncthreads();   // all m1 (normed q) reads done; m1 will hold hn (bf16)

  // ---- h += dec(qs) + dec_b; stash hn bf16 to m1 for the next-P GEMM ----
#pragma unroll
  for (int mt = 0; mt < 4; ++mt)
#pragma unroll
    for (int nt = 0; nt < 2; ++nt) {
      const int n = wbase + nt * 16 + lrow;
#pragma unroll
      for (int r = 0; r < 4; ++r) {
        const int node = n0 + mt * 16 + lq * 4 + r;
        float hn = 0.f;
        if (node < N_NODES) {
          size_t off = (size_t)node * HDIM + n;
          hn = out_h[off] + acc2[mt][nt][r] + dbv[nt];
          out_h[off] = hn;
        }
        m1[(mt * 16 + lq * 4 + r) * MS + n] = f2bf(hn);
      }
    }
  __syncthreads();   // hn tile ready

  // ---- next-stage P: P[node] = [hn@W1r + b1n | hn@W1c] (pgemm structure) --
  short8b wfp[4][4];
  const int csn = (wave >> 1) * 4;
  const int nbw = (wave & 1) * 64;
#pragma unroll
  for (int kt = 0; kt < 4; ++kt)
#pragma unroll
    for (int nt = 0; nt < 4; ++nt)
      wfp[kt][nt] = *(const short8b*)(w1n + (csn + kt) * 4096 + (nbw + nt * 16 + lrow) * 32 + lq * 8);
  f32x4 pacc[4][4];
#pragma unroll
  for (int mt = 0; mt < 4; ++mt)
#pragma unroll
    for (int nt = 0; nt < 4; ++nt) pacc[mt][nt] = (f32x4){0.f, 0.f, 0.f, 0.f};
#pragma unroll
  for (int kt = 0; kt < 4; ++kt) {
    short8b af[4];
#pragma unroll
    for (int mt = 0; mt < 4; ++mt)
      af[mt] = *(const short8b*)(m1 + (mt * 16 + lrow) * MS + kt * 32 + lq * 8);
#pragma unroll
    for (int mt = 0; mt < 4; ++mt)
#pragma unroll
      for (int nt = 0; nt < 4; ++nt)
        pacc[mt][nt] = __builtin_amdgcn_mfma_f32_16x16x32_bf16(af[mt], wfp[kt][nt], pacc[mt][nt], 0, 0, 0);
  }
  const int cbase = wave * 64;
#pragma unroll
  for (int nt = 0; nt < 4; ++nt) {
    const int ccol = cbase + nt * 16 + lrow;
    const float bb2 = (ccol < 128) ? b1n[ccol] : 0.f;
#pragma unroll
    for (int mt = 0; mt < 4; ++mt)
#pragma unroll
      for (int r = 0; r < 4; ++r) {
        const int node = n0 + mt * 16 + lq * 4 + r;
        if (node < N_NODES) Pout[(size_t)node * 256 + ccol] = f2bf(pacc[mt][nt][r] + bb2);
      }
  }
}

// ==================== coordinate head: EB=32, 128-thread blocks ============
__global__ __launch_bounds__(128, 8) void coord_mfma_kernel(
    const ushort* __restrict__ P, const unsigned int* __restrict__ rcp,
    const float2* __restrict__ era, const float* __restrict__ x,
    const float* __restrict__ wm,      // c_w1 rows 256,257 (f32)
    const ushort* __restrict__ w2cs, const float* __restrict__ b2,
    const float* __restrict__ w3, float* __restrict__ xout) {
  __shared__ ushort m1[EB * MS];
  __shared__ int rows[EB];
  __shared__ float pbuf[2 * EB];
  __shared__ float tv[EB];
  __shared__ float dxs[EB], dys[EB], dzs[EB], ses[EB];

  const int tid = threadIdx.x;
  const int lane = tid & 63, wave = tid >> 6;
  const int lrow = lane & 15, lq = lane >> 4;
  const int cb = wave * 64;

  const float b2v[4] = {b2[cb + lrow], b2[cb + 16 + lrow],
                        b2[cb + 32 + lrow], b2[cb + 48 + lrow]};
  const float w3v[4] = {w3[cb + lrow], w3[cb + 16 + lrow],
                        w3[cb + 32 + lrow], w3[cb + 48 + lrow]};

  const int i0 = blockIdx.x * EB;
  {
    const int e = tid >> 2, j = tid & 3;
    const unsigned int rcv = rcp[i0 + e];
    const int r = (int)(rcv & 0xFFFFu), c = (int)(rcv >> 16);
    if (j == 0) rows[e] = r;
    const float2 re2 = era[i0 + e];
    const float radial = re2.x, eav = re2.y;
    const uint4* pr = (const uint4*)(P + (size_t)r * 256 + j * 32);
    const uint4* pc = (const uint4*)(P + (size_t)c * 256 + 128 + j * 32);
    uint4 PR[4] = {pr[0], pr[1], pr[2], pr[3]};
    uint4 PC[4] = {pc[0], pc[1], pc[2], pc[3]};
    if (j == 3) {
      float dx = x[r * 3 + 0] - x[c * 3 + 0];
      float dy = x[r * 3 + 1] - x[c * 3 + 1];
      float dz = x[r * 3 + 2] - x[c * 3 + 2];
      dxs[e] = dx; dys[e] = dy; dzs[e] = dz;
      ses[e] = 1.0f / (sqrtf(radial + 1e-8f) + 1.0f);
    }
#pragma unroll
    for (int q = 0; q < 4; ++q) {
      const int kb = j * 32 + q * 8;
      const uint ua[4] = {PR[q].x, PR[q].y, PR[q].z, PR[q].w};
      const uint ub[4] = {PC[q].x, PC[q].y, PC[q].z, PC[q].w};
      uint ow[4];
#pragma unroll
      for (int w = 0; w < 4; ++w) {
        const int k = kb + w * 2;
        float v0 = __uint_as_float(ua[w] << 16) + __uint_as_float(ub[w] << 16)
                 + radial * wm[k] + eav * wm[128 + k];
        float v1 = __uint_as_float(ua[w] & 0xffff0000u) + __uint_as_float(ub[w] & 0xffff0000u)
                 + radial * wm[k + 1] + eav * wm[129 + k];
        ow[w] = cvt_pk_bf16(silu_f(v0), silu_f(v1));
      }
      uint4 o; o.x = ow[0]; o.y = ow[1]; o.z = ow[2]; o.w = ow[3];
      *(uint4*)(m1 + e * MS + kb) = o;
    }
  }
  __syncthreads();   // s1: m1 ready

  f32x4 acc2[2][4];
#pragma unroll
  for (int mt = 0; mt < 2; ++mt)
#pragma unroll
    for (int nt = 0; nt < 4; ++nt) acc2[mt][nt] = (f32x4){0.f, 0.f, 0.f, 0.f};
#pragma unroll
  for (int kt = 0; kt < 4; ++kt) {
    short8b wf[4];
#pragma unroll
    for (int nt = 0; nt < 4; ++nt)
      wf[nt] = *(const short8b*)(w2cs + kt * 4096 + (cb + nt * 16 + lrow) * 32 + lq * 8);
    short8b af[2];
#pragma unroll
    for (int mt = 0; mt < 2; ++mt)
      af[mt] = *(const short8b*)(m1 + (mt * 16 + lrow) * MS + kt * 32 + lq * 8);
#pragma unroll
    for (int mt = 0; mt < 2; ++mt)
#pragma unroll
      for (int nt = 0; nt < 4; ++nt)
        acc2[mt][nt] = __builtin_amdgcn_mfma_f32_16x16x32_bf16(af[mt], wf[nt], acc2[mt][nt], 0, 0, 0);
  }

  // ---- t-scalar: per-lane partial over the wave's 64 cols ----
#pragma unroll
  for (int mt = 0; mt < 2; ++mt) {
    float p[4] = {0.f, 0.f, 0.f, 0.f};
#pragma unroll
    for (int nt = 0; nt < 4; ++nt)
#pragma unroll
      for (int r = 0; r < 4; ++r)
        p[r] += silu_f(acc2[mt][nt][r] + b2v[nt]) * w3v[nt];
#pragma unroll
    for (int m = 1; m < 16; m <<= 1)
#pragma unroll
      for (int r = 0; r < 4; ++r) p[r] += __shfl_xor(p[r], m, 64);
    if (lrow == 0) {
#pragma unroll
      for (int r = 0; r < 4; ++r)
        pbuf[wave * EB + mt * 16 + lq * 4 + r] = p[r];
    }
  }
  __syncthreads();   // s2
  if (tid < EB) {
    tv[tid] = (pbuf[tid] + pbuf[EB + tid]) * 0.01f * ses[tid];
  }
  __syncthreads();   // s3: tv ready
  if (tid < EB) {
    const int e = tid;
    const int r_e = rows[e];
    const bool leader = (e == 0) || (rows[e - 1] != r_e);
    if (leader) {
      float sx = 0.f, sy = 0.f, sz = 0.f;
      int f = e;
      do {
        float t = tv[f];
        sx += dxs[f] * t; sy += dys[f] * t; sz += dzs[f] * t;
        ++f;
      } while (f < EB && rows[f] == r_e);
      atomicAdd(&xout[r_e * 3 + 0], sx);
      atomicAdd(&xout[r_e * 3 + 1], sy);
      atomicAdd(&xout[r_e * 3 + 2], sz);
    }
  }
}

extern "C" void kernel_launch(void* const* d_in, const int* in_sizes, int n_in,
                              void* d_out, int out_size, void* d_ws, size_t ws_size,
                              hipStream_t stream) {
  const float* h     = (const float*)d_in[0];
  const float* x     = (const float*)d_in[1];
  const int*   ei    = (const int*)d_in[2];
  const float* ea    = (const float*)d_in[3];
  const float* e_w1  = (const float*)d_in[4];
  const float* e_b1  = (const float*)d_in[5];
  const float* e_w2  = (const float*)d_in[6];
  const float* e_b2  = (const float*)d_in[7];
  const float* enc_w = (const float*)d_in[8];
  const float* enc_b = (const float*)d_in[9];
  const float* coeffs= (const float*)d_in[10];
  const float* A_re  = (const float*)d_in[11];
  const float* A_im  = (const float*)d_in[12];
  const float* dec_w = (const float*)d_in[13];
  const float* dec_b = (const float*)d_in[14];
  const float* c_w1  = (const float*)d_in[15];
  const float* c_b1  = (const float*)d_in[16];
  const float* c_w2  = (const float*)d_in[17];
  const float* c_b2  = (const float*)d_in[18];
  const float* c_w3  = (const float*)d_in[19];

  float* out = (float*)d_out;
  float* ws  = (float*)d_ws;

  // workspace layout (float offsets) — ~48.5 MB (headp grown to 15000x128)
  float*        agg    = ws;                          // 3,840,000
  float2*       xa     = (float2*)(ws + 3840000);     // 131,072 f
  float2*       xb     = (float2*)(ws + 3971072);     // 131,072 f
  float2*       xt     = (float2*)(ws + 4102144);     // 131,072 f
  float2*       qm     = (float2*)(ws + 4233216);     // 131,072 f
  float2*       gkm    = (float2*)(ws + 4364288);     // 131,072 f
  float2*       njm    = (float2*)(ws + 4495360);     // 131,072 f
  float2*       um     = (float2*)(ws + 4626432);     //  65,536 f
  int*          cursor = (int*)(ws + 4724864);        //  30,000 (post-fill: CSR ends)
  int*          cstart = (int*)(ws + 4754864);        //  30,000 (CSR starts)
  unsigned int* rcp    = (unsigned int*)(ws + 4784864); // 480,000 (r | c<<16, sorted)
  float2*       era    = (float2*)(ws + 5264864);     // 480,000 f2 = 960,000 f
  float*        headp  = ws + 6224864;                // 15000*128 = 1,920,000
  ushort*       w1cs   = (ushort*)(ws + 8144864);     // 36,864 f
  ushort*       w2cs   = (ushort*)(ws + 8181728);     // 16,384 f
  ushort*       cw1cs  = (ushort*)(ws + 8198112);     // 18,432 f
  ushort*       cw2cs  = (ushort*)(ws + 8216544);     //  8,192 f
  ushort*       enccs  = (ushort*)(ws + 8224736);     // 32,768 f
  ushort*       wqdcs  = (ushort*)(ws + 8257504);     // 16,384 f
  ushort*       Pbuf   = (ushort*)(ws + 8273888);     // 30000*256 bf16 = 3,840,000 f

  // init: out=[h|x], count histogram (cursor pre-zeroed)
  hipMemsetAsync(cursor, 0, N_NODES * sizeof(int), stream);
  init_out_bf_kernel<<<3750, 256, 0, stream>>>(h, x, ei, out, cursor);
  scan_kernel<<<1, 1024, 0, stream>>>(cursor, cstart);

  // merged prep: fill(rcp/era) + weight converts + ns_init + gk + layer0-P
  prep_kernel<<<3736, 256, 0, stream>>>(ei, cursor, rcp, era, x, ea,
                                        e_w1, e_w2, enc_w, c_w1, c_w2,
                                        w1cs, w2cs, enccs, cw1cs, cw2cs,
                                        A_re, A_im, xa, coeffs, gkm,
                                        out, e_b1, Pbuf);

  // Newton-Schulz (2 iterations) + tiny GEMM chain
  float2* cur = xa;
  float2* nxt = xb;
  for (int it = 0; it < 2; ++it) {
    ns_bx_kernel<<<dim3(64, 4), 256, 0, stream>>>(A_re, A_im, cur, xt);
    ns_upd_kernel<<<dim3(64, 4), 256, 0, stream>>>(cur, xt, nxt);
    float2* tmp = cur; cur = nxt; nxt = tmp;
  }
  qmat_kernel<<<dim3(64, 4), 256, 0, stream>>>(A_re, A_im, cur, qm);
  nj_kernel<<<dim3(64, 4), 256, 0, stream>>>(qm, gkm, njm);
  compose_kernel<<<dim3(64, 2), 256, 0, stream>>>(njm, um);
  wqd_kernel<<<dim3(64, 2), 256, 0, stream>>>(um, dec_w, wqdcs);

  const int NB = (N_NODES + EPB - 1) / EPB;   // 469

  // two message-passing layers; node kernel emits the NEXT stage's P
  for (int l = 0; l < 2; ++l) {
    edge_mfma_kernel<<<N_EDGES / EB, 128, 0, stream>>>(
        Pbuf, rcp, era, cstart,
        e_w1 + (size_t)l * 258 * HDIM + 256 * HDIM,
        w2cs + (size_t)l * 4 * 4096, e_b2 + l * HDIM, agg, headp);
    node_mfma_kernel<<<NB, 256, 0, stream>>>(
        out, agg, cstart, cursor, headp,
        enccs + (size_t)l * 8 * 4096, enc_b + l * HDIM,
        wqdcs + (size_t)l * 4 * 4096, dec_b + l * HDIM,
        (l == 0) ? (w1cs + (size_t)9 * 4096) : cw1cs,
        (l == 0) ? (e_b1 + HDIM) : c_b1,
        Pbuf);
  }

  // coordinate head
  coord_mfma_kernel<<<N_EDGES / EB, 128, 0, stream>>>(
      Pbuf, rcp, era, x, c_w1 + 256 * HDIM, cw2cs, c_b2, c_w3,
      out + (size_t)N_NODES * HDIM);
}

// Round 10
// 698.769 us; speedup vs baseline: 1.1232x; 1.1232x over previous
//
#include <hip/hip_runtime.h>
#include <math.h>

#define N_NODES 30000
#define N_EDGES 480000
#define HDIM 128
#define EPB 64        // nodes per node-kernel block
#define EB 32         // edges per edge/coord block (128 threads); any node
                      // degree is handled via multi-block headp continuation.
#define NAS 264       // node A-tile row stride (bf16)
#define MS 136        // m1 / Ht row stride (bf16)
#define M2TS 36       // transposed m2 row stride (bf16): [128 cols][36]

typedef __attribute__((ext_vector_type(8))) short short8b;
typedef __attribute__((ext_vector_type(4))) float f32x4;

__device__ __forceinline__ float silu_f(float v) {
  return v / (1.0f + __expf(-v));
}

__device__ __forceinline__ unsigned short f2bf(float f) {
  unsigned int u = __float_as_uint(f);
  unsigned int r = u + 0x7fffu + ((u >> 16) & 1u);
  return (unsigned short)(r >> 16);
}

// HW packed f32->bf16 (RNE, same rounding as f2bf): 1 instr replaces ~9.
__device__ __forceinline__ unsigned int cvt_pk_bf16(float lo, float hi) {
  unsigned int r;
  asm("v_cvt_pk_bf16_f32 %0, %1, %2" : "=v"(r) : "v"(lo), "v"(hi));
  return r;
}

__device__ __forceinline__ ushort4 pk4(float4 v) {
  uint2 u;
  u.x = cvt_pk_bf16(v.x, v.y);
  u.y = cvt_pk_bf16(v.z, v.w);
  return *(ushort4*)&u;
}

// ---- fused init: out = [h | x], edge count histogram ------
__global__ void init_out_bf_kernel(const float* __restrict__ h,
                                   const float* __restrict__ x,
                                   const int* __restrict__ ei,
                                   float* __restrict__ out,
                                   int* __restrict__ cursor) {
  int idx = blockIdx.x * 256 + threadIdx.x;   // 960,000 float4 units
  ((float4*)out)[idx] = ((const float4*)h)[idx];
  if (idx < N_NODES * 3 / 4) {
    ((float4*)(out + N_NODES * HDIM))[idx] = ((const float4*)x)[idx];
  }
  if (idx < N_EDGES) atomicAdd(&cursor[ei[idx]], 1);
}

__global__ __launch_bounds__(1024) void scan_kernel(int* __restrict__ cursor,
                                                    int* __restrict__ cstart) {
  __shared__ int sums[1024];
  const int tid = threadIdx.x;
  const int base = tid * 30;
  int local[30];
  int s = 0;
#pragma unroll
  for (int j = 0; j < 30; ++j) {
    int idx = base + j;
    int d = (idx < N_NODES) ? cursor[idx] : 0;
    local[j] = s;
    s += d;
  }
  sums[tid] = s;
  __syncthreads();
  for (int off = 1; off < 1024; off <<= 1) {
    int add = (tid >= off) ? sums[tid - off] : 0;
    __syncthreads();
    sums[tid] += add;
    __syncthreads();
  }
  int excl = (tid == 0) ? 0 : sums[tid - 1];
#pragma unroll
  for (int j = 0; j < 30; ++j) {
    int idx = base + j;
    if (idx < N_NODES) {
      int v = excl + local[j];
      cursor[idx] = v;
      cstart[idx] = v;   // immutable CSR starts (cursor mutates in fill)
    }
  }
}

// ---- merged post-scan prep: fill | weight-convert | ns_init | gk | l0-P ---
// block ranges: 0-1874 fill (writes sorted rcp/era), 1875-2754 convert
// (55 chunks), 2755-3010 ns_init, 3011-3266 gk, 3267-3735 pgemm for layer 0.
__global__ void prep_kernel(
    const int* __restrict__ ei, int* __restrict__ cursor,
    unsigned int* __restrict__ rcp, float2* __restrict__ era,
    const float* __restrict__ x, const float* __restrict__ ea,
    const float* __restrict__ e_w1, const float* __restrict__ e_w2,
    const float* __restrict__ enc_w, const float* __restrict__ c_w1,
    const float* __restrict__ c_w2,
    ushort* __restrict__ w1cs, ushort* __restrict__ w2cs,
    ushort* __restrict__ enccs, ushort* __restrict__ cw1cs,
    ushort* __restrict__ cw2cs,
    const float* __restrict__ A_re, const float* __restrict__ A_im,
    float2* __restrict__ X,
    const float* __restrict__ coeffs, float2* __restrict__ gkm,
    const float* __restrict__ outh, const float* __restrict__ b1l0,
    ushort* __restrict__ P) {
  __shared__ ushort Ht[EPB * MS];   // used by the pgemm range only
  const int b = blockIdx.x, tid = threadIdx.x;
  if (b < 1875) {
    int e = b * 256 + tid;
    int r = ei[e];
    int c = ei[N_EDGES + e];
    int pos = atomicAdd(&cursor[r], 1);   // after: cursor[n] = CSR end
    rcp[pos] = (unsigned int)r | ((unsigned int)c << 16);
    float dx = x[r * 3 + 0] - x[c * 3 + 0];
    float dy = x[r * 3 + 1] - x[c * 3 + 1];
    float dz = x[r * 3 + 2] - x[c * 3 + 2];
    era[pos] = make_float2(dx * dx + dy * dy + dz * dz, ea[e]);
  } else if (b < 2755) {
    int idx = (b - 1875) * 256 + tid;     // 0 .. 225279 (= 55*4096)
    int ci = idx >> 12, rem = idx & 4095, kk = rem & 31;
    const float* W; ushort* dst; int Kreal, ktl;
    if (ci < 18) {
      int l = ci / 9; ktl = ci - l * 9;
      W = e_w1 + (size_t)l * 258 * HDIM; dst = w1cs + (size_t)l * 9 * 4096;
      Kreal = 258;
    } else if (ci < 26) {
      int c2 = ci - 18; int l = c2 >> 2; ktl = c2 & 3;
      W = e_w2 + (size_t)l * HDIM * HDIM; dst = w2cs + (size_t)l * 4 * 4096;
      Kreal = 128;
    } else if (ci < 42) {
      int c2 = ci - 26; int l = c2 >> 3; ktl = c2 & 7;
      W = enc_w + (size_t)l * 256 * HDIM; dst = enccs + (size_t)l * 8 * 4096;
      Kreal = 256;
    } else if (ci < 51) {
      ktl = ci - 42; W = c_w1; dst = cw1cs; Kreal = 258;
    } else {
      ktl = ci - 51; W = c_w2; dst = cw2cs; Kreal = 128;
    }
    int n = rem >> 5;
    int k = ktl * 32 + kk;
    float v = (k < Kreal) ? W[(size_t)k * HDIM + n] : 0.0f;
    dst[ktl * 4096 + rem] = f2bf(v);
  } else if (b < 3011) {
    int bb = b - 2755;
    int lj = bb >> 6;
    int idx = (bb & 63) * 256 + tid;
    int r = idx >> 7, c = idx & 127;
    const float* are = A_re + (size_t)lj * 16384;
    const float* aim = A_im + (size_t)lj * 16384;
    float re = are[r * 128 + c] + are[c * 128 + r];
    float im = aim[r * 128 + c] - aim[c * 128 + r];
    if (r == c) im -= 1.0f;
    X[(size_t)lj * 16384 + idx] = make_float2(re, im);
  } else if (b < 3267) {
    int bb = b - 3011;
    int lj = bb >> 6;
    float a = coeffs[lj * 2 + 0], bcf = coeffs[lj * 2 + 1];
    float ca = cosf(0.5f * a), sa = sinf(0.5f * a);
    float cb = cosf(0.5f * bcf), sb = sinf(0.5f * bcf);
    float2 G[2][2];
    G[0][0] = make_float2(cb * ca, sb * sa);
    G[0][1] = make_float2(-sb * ca, -cb * sa);
    G[1][0] = make_float2(sb * ca, -cb * sa);
    G[1][1] = make_float2(cb * ca, -sb * sa);
    int idx = (bb & 63) * 256 + tid;
    int r = idx >> 7, c = idx & 127;
    float2 acc = make_float2(1.f, 0.f);
#pragma unroll
    for (int bit = 6; bit >= 0; --bit) {
      float2 g = G[(r >> bit) & 1][(c >> bit) & 1];
      acc = make_float2(acc.x * g.x - acc.y * g.y, acc.x * g.y + acc.y * g.x);
    }
    gkm[(size_t)lj * 16384 + idx] = acc;
  } else {
    // ---- pgemm for layer 0: P = [h@W1r + b1 | h@W1c], staged from out ----
    const int n0 = (b - 3267) * EPB;
    const int lane = tid & 63, wave = tid >> 6;
    const int lrow = lane & 15, lq = lane >> 4;
    {
      const int e = tid >> 2, jj = tid & 3;
      int node = n0 + e;
      if (node >= N_NODES) node = N_NODES - 1;
      const float4* s4 = (const float4*)(outh + (size_t)node * HDIM + jj * 32);
      ushort* dst = Ht + e * MS + jj * 32;
#pragma unroll
      for (int i = 0; i < 8; ++i) {
        ((ushort4*)dst)[i] = pk4(s4[i]);
      }
    }
    short8b wf[4][4];
    const int cs = (wave >> 1) * 4;     // waves 0,1 -> W1r; 2,3 -> W1c
    const int nb = (wave & 1) * 64;
#pragma unroll
    for (int kt = 0; kt < 4; ++kt)
#pragma unroll
      for (int nt = 0; nt < 4; ++nt)
        wf[kt][nt] = *(const short8b*)(w1cs + (cs + kt) * 4096 + (nb + nt * 16 + lrow) * 32 + lq * 8);
    __syncthreads();

    f32x4 acc[4][4];
#pragma unroll
    for (int mt = 0; mt < 4; ++mt)
#pragma unroll
      for (int nt = 0; nt < 4; ++nt) acc[mt][nt] = (f32x4){0.f, 0.f, 0.f, 0.f};
#pragma unroll
    for (int kt = 0; kt < 4; ++kt) {
      short8b af[4];
#pragma unroll
      for (int mt = 0; mt < 4; ++mt)
        af[mt] = *(const short8b*)(Ht + (mt * 16 + lrow) * MS + kt * 32 + lq * 8);
#pragma unroll
      for (int mt = 0; mt < 4; ++mt)
#pragma unroll
        for (int nt = 0; nt < 4; ++nt)
          acc[mt][nt] = __builtin_amdgcn_mfma_f32_16x16x32_bf16(af[mt], wf[kt][nt], acc[mt][nt], 0, 0, 0);
    }
    const int cbase = wave * 64;
#pragma unroll
    for (int nt = 0; nt < 4; ++nt) {
      const int ccol = cbase + nt * 16 + lrow;
      const float bb2 = (ccol < 128) ? b1l0[ccol] : 0.f;
#pragma unroll
      for (int mt = 0; mt < 4; ++mt)
#pragma unroll
        for (int r = 0; r < 4; ++r) {
          const int node = n0 + mt * 16 + lq * 4 + r;
          if (node < N_NODES) P[(size_t)node * 256 + ccol] = f2bf(acc[mt][nt][r] + bb2);
        }
    }
  }
}

// ============ Newton-Schulz inverse of B = A_h + iI (2 iterations) ========
__global__ void ns_bx_kernel(const float* __restrict__ Are,
                             const float* __restrict__ Aim,
                             const float2* __restrict__ X,
                             float2* __restrict__ T) {
  int lj = blockIdx.y;
  int idx = blockIdx.x * 256 + threadIdx.x;
  int r = idx >> 7, c = idx & 127;
  const float* are = Are + (size_t)lj * 16384;
  const float* aim = Aim + (size_t)lj * 16384;
  const float2* x = X + (size_t)lj * 16384;
  float2 acc = make_float2(0.f, 0.f);
  for (int k = 0; k < 128; ++k) {
    float re = are[r * 128 + k] + are[k * 128 + r];
    float im = aim[r * 128 + k] - aim[k * 128 + r];
    if (k == r) im += 1.0f;
    float2 b = x[k * 128 + c];
    acc.x += re * b.x - im * b.y;
    acc.y += re * b.y + im * b.x;
  }
  T[(size_t)lj * 16384 + idx] = acc;
}

__global__ void ns_upd_kernel(const float2* __restrict__ X,
                              const float2* __restrict__ T,
                              float2* __restrict__ Xn) {
  int lj = blockIdx.y;
  int idx = blockIdx.x * 256 + threadIdx.x;
  int r = idx >> 7, c = idx & 127;
  const float2* x = X + (size_t)lj * 16384;
  const float2* t = T + (size_t)lj * 16384;
  float2 acc = make_float2(0.f, 0.f);
  for (int k = 0; k < 128; ++k) {
    float2 a = x[r * 128 + k];
    float2 b = t[k * 128 + c];
    acc.x += a.x * b.x - a.y * b.y;
    acc.y += a.x * b.y + a.y * b.x;
  }
  float2 xc = x[r * 128 + c];
  Xn[(size_t)lj * 16384 + idx] = make_float2(2.f * xc.x - acc.x, 2.f * xc.y - acc.y);
}

// ---------------- q = (A_h - iI) * Binv ----------------
__global__ void qmat_kernel(const float* __restrict__ Are,
                            const float* __restrict__ Aim,
                            const float2* __restrict__ binvg,
                            float2* __restrict__ qm) {
  int lj = blockIdx.y;
  int idx = blockIdx.x * 256 + threadIdx.x;
  int r = idx >> 7, c = idx & 127;
  const float* are = Are + (size_t)lj * 16384;
  const float* aim = Aim + (size_t)lj * 16384;
  const float2* binv = binvg + (size_t)lj * 16384;
  float2 acc = make_float2(0.f, 0.f);
  for (int k = 0; k < 128; ++k) {
    float re = are[r * 128 + k] + are[k * 128 + r];
    float im = aim[r * 128 + k] - aim[k * 128 + r];
    if (k == r) im -= 1.0f;
    float2 b = binv[k * 128 + c];
    acc.x += re * b.x - im * b.y;
    acc.y += re * b.y + im * b.x;
  }
  qm[(size_t)lj * 16384 + idx] = acc;
}

// ------- N_j[i][c] = sum_k q[k][i] * Gk[g[c]][k]  (CNOT perm inlined) ------
__global__ void nj_kernel(const float2* __restrict__ qm,
                          const float2* __restrict__ gkm,
                          float2* __restrict__ njm) {
  int lj = blockIdx.y;
  int idx = blockIdx.x * 256 + threadIdx.x;
  int i = idx >> 7, c = idx & 127;
  int gc;
  {
    int v = c;
    const int cs[7] = {6, 5, 4, 3, 2, 1, 0};
    const int ts[7] = {0, 6, 5, 4, 3, 2, 1};
#pragma unroll
    for (int p = 0; p < 7; ++p) {
      int cb = (v >> (6 - cs[p])) & 1;
      v = v ^ (cb << (6 - ts[p]));
    }
    gc = v;
  }
  const float2* q = qm + (size_t)lj * 16384;
  const float2* gk = gkm + (size_t)lj * 16384;
  float2 acc = make_float2(0.f, 0.f);
  for (int k = 0; k < 128; ++k) {
    float2 qa = q[k * 128 + i];
    float2 gb = gk[gc * 128 + k];
    acc.x += qa.x * gb.x - qa.y * gb.y;
    acc.y += qa.x * gb.y + qa.y * gb.x;
  }
  njm[(size_t)lj * 16384 + idx] = acc;
}

// ---------------- U_l = N_{l,0} @ N_{l,1} ----------------
__global__ void compose_kernel(const float2* __restrict__ njm,
                               float2* __restrict__ um) {
  int l = blockIdx.y;
  int idx = blockIdx.x * 256 + threadIdx.x;
  int i = idx >> 7, c = idx & 127;
  const float2* n0 = njm + (size_t)(l * 2 + 0) * 16384;
  const float2* n1 = njm + (size_t)(l * 2 + 1) * 16384;
  float2 acc = make_float2(0.f, 0.f);
  for (int k = 0; k < 128; ++k) {
    float2 a = n0[i * 128 + k];
    float2 b = n1[k * 128 + c];
    acc.x += a.x * b.x - a.y * b.y;
    acc.y += a.x * b.y + a.y * b.x;
  }
  um[(size_t)l * 16384 + idx] = acc;
}

// -------- Wqd_l = Re(U_l) @ dec_w_l, written DIRECTLY as bf16 chunks -------
__global__ void wqd_kernel(const float2* __restrict__ um,
                           const float* __restrict__ decw,
                           ushort* __restrict__ wqdcs) {
  int l = blockIdx.y;
  int idx = blockIdx.x * 256 + threadIdx.x;
  int i = idx >> 7, c = idx & 127;     // i = k-dim (D), c = n-dim (H)
  const float2* u = um + (size_t)l * 16384;
  const float* dw = decw + (size_t)l * 16384;
  float acc = 0.f;
  for (int k = 0; k < 128; ++k) acc += u[i * 128 + k].x * dw[k * 128 + c];
  wqdcs[(size_t)l * 4 * 4096 + (i >> 5) * 4096 + c * 32 + (i & 31)] = f2bf(acc);
}

// ==================== edge MLP: EB=32, 128-thread blocks ===================
// Round-10: identical to round-9 EXCEPT launch_bounds(128,4). Round-9's
// (128,8) demanded 8 waves/SIMD -> 64-reg cap on the UNIFIED VGPR+AGPR file;
// true demand ~85 -> 120B/thread scratch spill (WRITE 248MB). With cap 128
// the allocator fits everything; occupancy floats to the resource limit
// (~6 waves/SIMD = 12 independent 2-wave blocks/CU for phase overlap).
__global__ __launch_bounds__(128, 4) void edge_mfma_kernel(
    const ushort* __restrict__ P, const unsigned int* __restrict__ rcp,
    const float2* __restrict__ era, const int* __restrict__ cstart,
    const float* __restrict__ wm,      // f32: [0:128]=radial row, [128:256]=ea row
    const ushort* __restrict__ w2cs, const float* __restrict__ b2,
    float* __restrict__ agg, float* __restrict__ headp) {
  __shared__ ushort buf[128 * M2TS];     // m1 (32x136=4352 us) / m2t (4608 us)
  __shared__ int rows[EB];
  __shared__ __align__(16) ushort segv[EB];
  __shared__ int segnode[EB];
  __shared__ int scont, snseg;
  ushort* m1 = buf;
  ushort* m2t = buf;

  const int tid = threadIdx.x;
  const int lane = tid & 63, wave = tid >> 6;
  const int lrow = lane & 15, lq = lane >> 4;
  const int cb = wave * 64;              // this wave's 64 output cols
  const float b2v[4] = {b2[cb + lrow], b2[cb + 16 + lrow],
                        b2[cb + 32 + lrow], b2[cb + 48 + lrow]};

  const int i0 = blockIdx.x * EB;
  {
    const int e = tid >> 2, j = tid & 3;
    const unsigned int rcv = rcp[i0 + e];
    const int r = (int)(rcv & 0xFFFFu), c = (int)(rcv >> 16);
    if (j == 0) rows[e] = r;
    const float2 re2 = era[i0 + e];
    const float radial = re2.x, eav = re2.y;
    const uint4* pr = (const uint4*)(P + (size_t)r * 256 + j * 32);
    const uint4* pc = (const uint4*)(P + (size_t)c * 256 + 128 + j * 32);
    uint4 PR[4] = {pr[0], pr[1], pr[2], pr[3]};
    uint4 PC[4] = {pc[0], pc[1], pc[2], pc[3]};
#pragma unroll
    for (int q = 0; q < 4; ++q) {
      const int kb = j * 32 + q * 8;
      const uint ua[4] = {PR[q].x, PR[q].y, PR[q].z, PR[q].w};
      const uint ub[4] = {PC[q].x, PC[q].y, PC[q].z, PC[q].w};
      uint ow[4];
#pragma unroll
      for (int w = 0; w < 4; ++w) {
        const int k = kb + w * 2;
        float v0 = __uint_as_float(ua[w] << 16) + __uint_as_float(ub[w] << 16)
                 + radial * wm[k] + eav * wm[128 + k];
        float v1 = __uint_as_float(ua[w] & 0xffff0000u) + __uint_as_float(ub[w] & 0xffff0000u)
                 + radial * wm[k + 1] + eav * wm[129 + k];
        ow[w] = cvt_pk_bf16(silu_f(v0), silu_f(v1));
      }
      uint4 o; o.x = ow[0]; o.y = ow[1]; o.z = ow[2]; o.w = ow[3];
      *(uint4*)(m1 + e * MS + kb) = o;
    }
  }
  __syncthreads();   // s1: m1 ready

  // ---- GEMM2: 2 edge-tiles x 4 col-tiles per wave ----
  f32x4 acc2[2][4];
#pragma unroll
  for (int mt = 0; mt < 2; ++mt)
#pragma unroll
    for (int nt = 0; nt < 4; ++nt) acc2[mt][nt] = (f32x4){0.f, 0.f, 0.f, 0.f};
#pragma unroll
  for (int kt = 0; kt < 4; ++kt) {
    short8b wf[4];
#pragma unroll
    for (int nt = 0; nt < 4; ++nt)
      wf[nt] = *(const short8b*)(w2cs + kt * 4096 + (cb + nt * 16 + lrow) * 32 + lq * 8);
    short8b af[2];
#pragma unroll
    for (int mt = 0; mt < 2; ++mt)
      af[mt] = *(const short8b*)(m1 + (mt * 16 + lrow) * MS + kt * 32 + lq * 8);
#pragma unroll
    for (int mt = 0; mt < 2; ++mt)
#pragma unroll
      for (int nt = 0; nt < 4; ++nt)
        acc2[mt][nt] = __builtin_amdgcn_mfma_f32_16x16x32_bf16(af[mt], wf[nt], acc2[mt][nt], 0, 0, 0);
  }
  __syncthreads();   // s2: all m1 reads done (m2t overlays)

  // m2 (bf16, transposed [col][edge]) written packed (cvt_pk + b64 store);
  // each wave writes ALL 32 edges of its own 64 cols.
#pragma unroll
  for (int mt = 0; mt < 2; ++mt)
#pragma unroll
    for (int nt = 0; nt < 4; ++nt) {
      const int col = cb + nt * 16 + lrow;
      uint2 u;
      u.x = cvt_pk_bf16(silu_f(acc2[mt][nt][0] + b2v[nt]),
                        silu_f(acc2[mt][nt][1] + b2v[nt]));
      u.y = cvt_pk_bf16(silu_f(acc2[mt][nt][2] + b2v[nt]),
                        silu_f(acc2[mt][nt][3] + b2v[nt]));
      *(uint2*)(m2t + col * M2TS + mt * 16 + lq * 4) = u;
    }
  if (wave == 0) {
    const int e = lane;
    const bool valid = e < EB;
    const int re_ = rows[valid ? e : (EB - 1)];
    const bool leader = valid && (e == 0 || rows[e - 1] != re_);
    const unsigned long long mask = __ballot(leader);
    if (valid) {
      const int seg = (int)__popcll(mask & ((1ull << e) - 1ull));
      segv[e] = (ushort)seg;
      if (leader) segnode[seg] = re_;
    }
    if (e == 0) {
      snseg = (int)__popcll(mask);
      scont = (cstart[re_] < i0) ? 1 : 0;
    }
  }
  __syncthreads();   // s3: m2t + seg ready

  // indicator GEMM (K=32): OUT[m2col][seg] = sum_e m2t[col][e]*(segv[e]==seg)
  const int nseg = snseg, cont = scont;
  const int ntmax = (nseg + 15) >> 4;     // usually 1
  const short8b sv = *(const short8b*)(segv + lq * 8);
  short8b afr[4];
#pragma unroll
  for (int mi = 0; mi < 4; ++mi)
    afr[mi] = *(const short8b*)(m2t + (cb + mi * 16 + lrow) * M2TS + lq * 8);
  for (int nt = 0; nt < ntmax; ++nt) {    // block-uniform
    const int tgt = nt * 16 + lrow;
    uint p[4];
#pragma unroll
    for (int w = 0; w < 4; ++w) {
      p[w] = (((int)(ushort)sv[2 * w] == tgt) ? 0x3F80u : 0u)
           | (((int)(ushort)sv[2 * w + 1] == tgt) ? 0x3F800000u : 0u);
    }
    uint4 u0 = make_uint4(p[0], p[1], p[2], p[3]);
    const short8b bf = *(const short8b*)&u0;
    f32x4 racc[4];
#pragma unroll
    for (int mi = 0; mi < 4; ++mi) {
      racc[mi] = (f32x4){0.f, 0.f, 0.f, 0.f};
      racc[mi] = __builtin_amdgcn_mfma_f32_16x16x32_bf16(afr[mi], bf, racc[mi], 0, 0, 0);
    }
    const int seg = tgt;
    if (seg < nseg) {
      const int node = segnode[seg];
      float* dst = (seg == 0 && cont) ? (headp + (size_t)blockIdx.x * HDIM)
                                      : (agg + (size_t)node * HDIM);
#pragma unroll
      for (int mi = 0; mi < 4; ++mi)
#pragma unroll
        for (int r = 0; r < 4; ++r)
          dst[cb + mi * 16 + lq * 4 + r] = racc[mi][r];
    }
  }
}

// ==================== MFMA node update (folds headp, emits next-layer P) ===
__global__ __launch_bounds__(256, 2) void node_mfma_kernel(
    float* __restrict__ out_h, const float* __restrict__ agg,
    const int* __restrict__ cstart, const int* __restrict__ cend,
    const float* __restrict__ headp,
    const ushort* __restrict__ enccs, const float* __restrict__ encb,
    const ushort* __restrict__ wqdcs, const float* __restrict__ decb,
    const ushort* __restrict__ w1n, const float* __restrict__ b1n,
    ushort* __restrict__ Pout) {
  __shared__ ushort A[EPB * NAS];
  __shared__ ushort m1[EPB * MS];
  __shared__ float nbuf[4 * EPB];
  const int tid = threadIdx.x;
  const int n0 = blockIdx.x * EPB;

  const int lane = tid & 63, wave = tid >> 6;
  const int lrow = lane & 15, lq = lane >> 4;
  const int wbase = wave * 32;

  short8b wef[8][2], wqf[4][2];
#pragma unroll
  for (int kt = 0; kt < 8; ++kt)
#pragma unroll
    for (int nt = 0; nt < 2; ++nt)
      wef[kt][nt] = *(const short8b*)(enccs + kt * 4096 + (wbase + nt * 16 + lrow) * 32 + lq * 8);
#pragma unroll
  for (int kt = 0; kt < 4; ++kt)
#pragma unroll
    for (int nt = 0; nt < 2; ++nt)
      wqf[kt][nt] = *(const short8b*)(wqdcs + kt * 4096 + (wbase + nt * 16 + lrow) * 32 + lq * 8);
  const float ebv[2] = {encb[wbase + lrow], encb[wbase + 16 + lrow]};
  const float dbv[2] = {decb[wbase + lrow], decb[wbase + 16 + lrow]};

  {
    const int e = tid >> 2, j = tid & 3;
    int node = n0 + e;
    if (node >= N_NODES) node = N_NODES - 1;
    if (j < 2) {
      const float4* s4 = (const float4*)(out_h + (size_t)node * HDIM + j * 64);
      ushort* dst = A + e * NAS + j * 64;
#pragma unroll
      for (int i = 0; i < 16; ++i) {
        ((ushort4*)dst)[i] = pk4(s4[i]);
      }
    } else {
      const int s = cstart[node], en = cend[node];
      const bool hasAgg = en > s;
      const float4* a4 = (const float4*)(agg + (size_t)node * HDIM + (j - 2) * 64);
      const int bb0 = (s >> 5) + 1;            // EB=32 edge blocks
      const int bb1 = hasAgg ? ((en - 1) >> 5) : 0;
      ushort* dst = A + e * NAS + 128 + (j - 2) * 64;
#pragma unroll
      for (int i = 0; i < 16; ++i) {
        float4 v = hasAgg ? a4[i] : make_float4(0.f, 0.f, 0.f, 0.f);
        for (int bb = bb0; bb <= bb1; ++bb) {
          float4 hv = *(const float4*)(headp + (size_t)bb * HDIM + (j - 2) * 64 + i * 4);
          v.x += hv.x; v.y += hv.y; v.z += hv.z; v.w += hv.w;
        }
        float4 sv = make_float4(v.x * 0.01f, v.y * 0.01f, v.z * 0.01f, v.w * 0.01f);
        ((ushort4*)dst)[i] = pk4(sv);
      }
    }
  }
  __syncthreads();

  f32x4 acc[4][2];
#pragma unroll
  for (int mt = 0; mt < 4; ++mt)
#pragma unroll
    for (int nt = 0; nt < 2; ++nt) acc[mt][nt] = (f32x4){0.f, 0.f, 0.f, 0.f};
#pragma unroll
  for (int kt = 0; kt < 8; ++kt) {
    short8b af[4];
#pragma unroll
    for (int mt = 0; mt < 4; ++mt)
      af[mt] = *(const short8b*)(A + (mt * 16 + lrow) * NAS + kt * 32 + lq * 8);
#pragma unroll
    for (int mt = 0; mt < 4; ++mt)
#pragma unroll
      for (int nt = 0; nt < 2; ++nt)
        acc[mt][nt] = __builtin_amdgcn_mfma_f32_16x16x32_bf16(af[mt], wef[kt][nt], acc[mt][nt], 0, 0, 0);
  }
#pragma unroll
  for (int mt = 0; mt < 4; ++mt) {
    float ssp[4] = {0.f, 0.f, 0.f, 0.f};
#pragma unroll
    for (int nt = 0; nt < 2; ++nt)
#pragma unroll
      for (int r = 0; r < 4; ++r) {
        acc[mt][nt][r] += ebv[nt];
        ssp[r] += acc[mt][nt][r] * acc[mt][nt][r];
      }
#pragma unroll
    for (int m = 1; m < 16; m <<= 1)
#pragma unroll
      for (int r = 0; r < 4; ++r) ssp[r] += __shfl_xor(ssp[r], m, 64);
    if (lrow == 0) {
#pragma unroll
      for (int r = 0; r < 4; ++r)
        nbuf[wave * EPB + mt * 16 + lq * 4 + r] = ssp[r];
    }
  }
  __syncthreads();
#pragma unroll
  for (int mt = 0; mt < 4; ++mt)
#pragma unroll
    for (int r = 0; r < 4; ++r) {
      const int row = mt * 16 + lq * 4 + r;
      float sum = nbuf[row] + nbuf[EPB + row] + nbuf[2 * EPB + row] + nbuf[3 * EPB + row];
      float inv = 1.0f / sqrtf(sum + 1e-12f);
#pragma unroll
      for (int nt = 0; nt < 2; ++nt)
        m1[row * MS + wbase + nt * 16 + lrow] = f2bf(acc[mt][nt][r] * inv);
    }
  __syncthreads();

  f32x4 acc2[4][2];
#pragma unroll
  for (int mt = 0; mt < 4; ++mt)
#pragma unroll
    for (int nt = 0; nt < 2; ++nt) acc2[mt][nt] = (f32x4){0.f, 0.f, 0.f, 0.f};
#pragma unroll
  for (int kt = 0; kt < 4; ++kt) {
    short8b af[4];
#pragma unroll
    for (int mt = 0; mt < 4; ++mt)
      af[mt] = *(const short8b*)(m1 + (mt * 16 + lrow) * MS + kt * 32 + lq * 8);
#pragma unroll
    for (int mt = 0; mt < 4; ++mt)
#pragma unroll
      for (int nt = 0; nt < 2; ++nt)
        acc2[mt][nt] = __builtin_amdgcn_mfma_f32_16x16x32_bf16(af[mt], wqf[kt][nt], acc2[mt][nt], 0, 0, 0);
  }
  __syncthreads();   // all m1 (normed q) reads done; m1 will hold hn (bf16)

  // ---- h += dec(qs) + dec_b; stash hn bf16 to m1 for the next-P GEMM ----
#pragma unroll
  for (int mt = 0; mt < 4; ++mt)
#pragma unroll
    for (int nt = 0; nt < 2; ++nt) {
      const int n = wbase + nt * 16 + lrow;
#pragma unroll
      for (int r = 0; r < 4; ++r) {
        const int node = n0 + mt * 16 + lq * 4 + r;
        float hn = 0.f;
        if (node < N_NODES) {
          size_t off = (size_t)node * HDIM + n;
          hn = out_h[off] + acc2[mt][nt][r] + dbv[nt];
          out_h[off] = hn;
        }
        m1[(mt * 16 + lq * 4 + r) * MS + n] = f2bf(hn);
      }
    }
  __syncthreads();   // hn tile ready

  // ---- next-stage P: P[node] = [hn@W1r + b1n | hn@W1c] (pgemm structure) --
  short8b wfp[4][4];
  const int csn = (wave >> 1) * 4;
  const int nbw = (wave & 1) * 64;
#pragma unroll
  for (int kt = 0; kt < 4; ++kt)
#pragma unroll
    for (int nt = 0; nt < 4; ++nt)
      wfp[kt][nt] = *(const short8b*)(w1n + (csn + kt) * 4096 + (nbw + nt * 16 + lrow) * 32 + lq * 8);
  f32x4 pacc[4][4];
#pragma unroll
  for (int mt = 0; mt < 4; ++mt)
#pragma unroll
    for (int nt = 0; nt < 4; ++nt) pacc[mt][nt] = (f32x4){0.f, 0.f, 0.f, 0.f};
#pragma unroll
  for (int kt = 0; kt < 4; ++kt) {
    short8b af[4];
#pragma unroll
    for (int mt = 0; mt < 4; ++mt)
      af[mt] = *(const short8b*)(m1 + (mt * 16 + lrow) * MS + kt * 32 + lq * 8);
#pragma unroll
    for (int mt = 0; mt < 4; ++mt)
#pragma unroll
      for (int nt = 0; nt < 4; ++nt)
        pacc[mt][nt] = __builtin_amdgcn_mfma_f32_16x16x32_bf16(af[mt], wfp[kt][nt], pacc[mt][nt], 0, 0, 0);
  }
  const int cbase = wave * 64;
#pragma unroll
  for (int nt = 0; nt < 4; ++nt) {
    const int ccol = cbase + nt * 16 + lrow;
    const float bb2 = (ccol < 128) ? b1n[ccol] : 0.f;
#pragma unroll
    for (int mt = 0; mt < 4; ++mt)
#pragma unroll
      for (int r = 0; r < 4; ++r) {
        const int node = n0 + mt * 16 + lq * 4 + r;
        if (node < N_NODES) Pout[(size_t)node * 256 + ccol] = f2bf(pacc[mt][nt][r] + bb2);
      }
  }
}

// ==================== coordinate head: EB=32, 128-thread blocks ============
__global__ __launch_bounds__(128, 4) void coord_mfma_kernel(
    const ushort* __restrict__ P, const unsigned int* __restrict__ rcp,
    const float2* __restrict__ era, const float* __restrict__ x,
    const float* __restrict__ wm,      // c_w1 rows 256,257 (f32)
    const ushort* __restrict__ w2cs, const float* __restrict__ b2,
    const float* __restrict__ w3, float* __restrict__ xout) {
  __shared__ ushort m1[EB * MS];
  __shared__ int rows[EB];
  __shared__ float pbuf[2 * EB];
  __shared__ float tv[EB];
  __shared__ float dxs[EB], dys[EB], dzs[EB], ses[EB];

  const int tid = threadIdx.x;
  const int lane = tid & 63, wave = tid >> 6;
  const int lrow = lane & 15, lq = lane >> 4;
  const int cb = wave * 64;

  const float b2v[4] = {b2[cb + lrow], b2[cb + 16 + lrow],
                        b2[cb + 32 + lrow], b2[cb + 48 + lrow]};
  const float w3v[4] = {w3[cb + lrow], w3[cb + 16 + lrow],
                        w3[cb + 32 + lrow], w3[cb + 48 + lrow]};

  const int i0 = blockIdx.x * EB;
  {
    const int e = tid >> 2, j = tid & 3;
    const unsigned int rcv = rcp[i0 + e];
    const int r = (int)(rcv & 0xFFFFu), c = (int)(rcv >> 16);
    if (j == 0) rows[e] = r;
    const float2 re2 = era[i0 + e];
    const float radial = re2.x, eav = re2.y;
    const uint4* pr = (const uint4*)(P + (size_t)r * 256 + j * 32);
    const uint4* pc = (const uint4*)(P + (size_t)c * 256 + 128 + j * 32);
    uint4 PR[4] = {pr[0], pr[1], pr[2], pr[3]};
    uint4 PC[4] = {pc[0], pc[1], pc[2], pc[3]};
    if (j == 3) {
      float dx = x[r * 3 + 0] - x[c * 3 + 0];
      float dy = x[r * 3 + 1] - x[c * 3 + 1];
      float dz = x[r * 3 + 2] - x[c * 3 + 2];
      dxs[e] = dx; dys[e] = dy; dzs[e] = dz;
      ses[e] = 1.0f / (sqrtf(radial + 1e-8f) + 1.0f);
    }
#pragma unroll
    for (int q = 0; q < 4; ++q) {
      const int kb = j * 32 + q * 8;
      const uint ua[4] = {PR[q].x, PR[q].y, PR[q].z, PR[q].w};
      const uint ub[4] = {PC[q].x, PC[q].y, PC[q].z, PC[q].w};
      uint ow[4];
#pragma unroll
      for (int w = 0; w < 4; ++w) {
        const int k = kb + w * 2;
        float v0 = __uint_as_float(ua[w] << 16) + __uint_as_float(ub[w] << 16)
                 + radial * wm[k] + eav * wm[128 + k];
        float v1 = __uint_as_float(ua[w] & 0xffff0000u) + __uint_as_float(ub[w] & 0xffff0000u)
                 + radial * wm[k + 1] + eav * wm[129 + k];
        ow[w] = cvt_pk_bf16(silu_f(v0), silu_f(v1));
      }
      uint4 o; o.x = ow[0]; o.y = ow[1]; o.z = ow[2]; o.w = ow[3];
      *(uint4*)(m1 + e * MS + kb) = o;
    }
  }
  __syncthreads();   // s1: m1 ready

  f32x4 acc2[2][4];
#pragma unroll
  for (int mt = 0; mt < 2; ++mt)
#pragma unroll
    for (int nt = 0; nt < 4; ++nt) acc2[mt][nt] = (f32x4){0.f, 0.f, 0.f, 0.f};
#pragma unroll
  for (int kt = 0; kt < 4; ++kt) {
    short8b wf[4];
#pragma unroll
    for (int nt = 0; nt < 4; ++nt)
      wf[nt] = *(const short8b*)(w2cs + kt * 4096 + (cb + nt * 16 + lrow) * 32 + lq * 8);
    short8b af[2];
#pragma unroll
    for (int mt = 0; mt < 2; ++mt)
      af[mt] = *(const short8b*)(m1 + (mt * 16 + lrow) * MS + kt * 32 + lq * 8);
#pragma unroll
    for (int mt = 0; mt < 2; ++mt)
#pragma unroll
      for (int nt = 0; nt < 4; ++nt)
        acc2[mt][nt] = __builtin_amdgcn_mfma_f32_16x16x32_bf16(af[mt], wf[nt], acc2[mt][nt], 0, 0, 0);
  }

  // ---- t-scalar: per-lane partial over the wave's 64 cols ----
#pragma unroll
  for (int mt = 0; mt < 2; ++mt) {
    float p[4] = {0.f, 0.f, 0.f, 0.f};
#pragma unroll
    for (int nt = 0; nt < 4; ++nt)
#pragma unroll
      for (int r = 0; r < 4; ++r)
        p[r] += silu_f(acc2[mt][nt][r] + b2v[nt]) * w3v[nt];
#pragma unroll
    for (int m = 1; m < 16; m <<= 1)
#pragma unroll
      for (int r = 0; r < 4; ++r) p[r] += __shfl_xor(p[r], m, 64);
    if (lrow == 0) {
#pragma unroll
      for (int r = 0; r < 4; ++r)
        pbuf[wave * EB + mt * 16 + lq * 4 + r] = p[r];
    }
  }
  __syncthreads();   // s2
  if (tid < EB) {
    tv[tid] = (pbuf[tid] + pbuf[EB + tid]) * 0.01f * ses[tid];
  }
  __syncthreads();   // s3: tv ready
  if (tid < EB) {
    const int e = tid;
    const int r_e = rows[e];
    const bool leader = (e == 0) || (rows[e - 1] != r_e);
    if (leader) {
      float sx = 0.f, sy = 0.f, sz = 0.f;
      int f = e;
      do {
        float t = tv[f];
        sx += dxs[f] * t; sy += dys[f] * t; sz += dzs[f] * t;
        ++f;
      } while (f < EB && rows[f] == r_e);
      atomicAdd(&xout[r_e * 3 + 0], sx);
      atomicAdd(&xout[r_e * 3 + 1], sy);
      atomicAdd(&xout[r_e * 3 + 2], sz);
    }
  }
}

extern "C" void kernel_launch(void* const* d_in, const int* in_sizes, int n_in,
                              void* d_out, int out_size, void* d_ws, size_t ws_size,
                              hipStream_t stream) {
  const float* h     = (const float*)d_in[0];
  const float* x     = (const float*)d_in[1];
  const int*   ei    = (const int*)d_in[2];
  const float* ea    = (const float*)d_in[3];
  const float* e_w1  = (const float*)d_in[4];
  const float* e_b1  = (const float*)d_in[5];
  const float* e_w2  = (const float*)d_in[6];
  const float* e_b2  = (const float*)d_in[7];
  const float* enc_w = (const float*)d_in[8];
  const float* enc_b = (const float*)d_in[9];
  const float* coeffs= (const float*)d_in[10];
  const float* A_re  = (const float*)d_in[11];
  const float* A_im  = (const float*)d_in[12];
  const float* dec_w = (const float*)d_in[13];
  const float* dec_b = (const float*)d_in[14];
  const float* c_w1  = (const float*)d_in[15];
  const float* c_b1  = (const float*)d_in[16];
  const float* c_w2  = (const float*)d_in[17];
  const float* c_b2  = (const float*)d_in[18];
  const float* c_w3  = (const float*)d_in[19];

  float* out = (float*)d_out;
  float* ws  = (float*)d_ws;

  // workspace layout (float offsets) — ~48.5 MB (headp 15000x128)
  float*        agg    = ws;                          // 3,840,000
  float2*       xa     = (float2*)(ws + 3840000);     // 131,072 f
  float2*       xb     = (float2*)(ws + 3971072);     // 131,072 f
  float2*       xt     = (float2*)(ws + 4102144);     // 131,072 f
  float2*       qm     = (float2*)(ws + 4233216);     // 131,072 f
  float2*       gkm    = (float2*)(ws + 4364288);     // 131,072 f
  float2*       njm    = (float2*)(ws + 4495360);     // 131,072 f
  float2*       um     = (float2*)(ws + 4626432);     //  65,536 f
  int*          cursor = (int*)(ws + 4724864);        //  30,000 (post-fill: CSR ends)
  int*          cstart = (int*)(ws + 4754864);        //  30,000 (CSR starts)
  unsigned int* rcp    = (unsigned int*)(ws + 4784864); // 480,000 (r | c<<16, sorted)
  float2*       era    = (float2*)(ws + 5264864);     // 480,000 f2 = 960,000 f
  float*        headp  = ws + 6224864;                // 15000*128 = 1,920,000
  ushort*       w1cs   = (ushort*)(ws + 8144864);     // 36,864 f
  ushort*       w2cs   = (ushort*)(ws + 8181728);     // 16,384 f
  ushort*       cw1cs  = (ushort*)(ws + 8198112);     // 18,432 f
  ushort*       cw2cs  = (ushort*)(ws + 8216544);     //  8,192 f
  ushort*       enccs  = (ushort*)(ws + 8224736);     // 32,768 f
  ushort*       wqdcs  = (ushort*)(ws + 8257504);     // 16,384 f
  ushort*       Pbuf   = (ushort*)(ws + 8273888);     // 30000*256 bf16 = 3,840,000 f

  // init: out=[h|x], count histogram (cursor pre-zeroed)
  hipMemsetAsync(cursor, 0, N_NODES * sizeof(int), stream);
  init_out_bf_kernel<<<3750, 256, 0, stream>>>(h, x, ei, out, cursor);
  scan_kernel<<<1, 1024, 0, stream>>>(cursor, cstart);

  // merged prep: fill(rcp/era) + weight converts + ns_init + gk + layer0-P
  prep_kernel<<<3736, 256, 0, stream>>>(ei, cursor, rcp, era, x, ea,
                                        e_w1, e_w2, enc_w, c_w1, c_w2,
                                        w1cs, w2cs, enccs, cw1cs, cw2cs,
                                        A_re, A_im, xa, coeffs, gkm,
                                        out, e_b1, Pbuf);

  // Newton-Schulz (2 iterations) + tiny GEMM chain
  float2* cur = xa;
  float2* nxt = xb;
  for (int it = 0; it < 2; ++it) {
    ns_bx_kernel<<<dim3(64, 4), 256, 0, stream>>>(A_re, A_im, cur, xt);
    ns_upd_kernel<<<dim3(64, 4), 256, 0, stream>>>(cur, xt, nxt);
    float2* tmp = cur; cur = nxt; nxt = tmp;
  }
  qmat_kernel<<<dim3(64, 4), 256, 0, stream>>>(A_re, A_im, cur, qm);
  nj_kernel<<<dim3(64, 4), 256, 0, stream>>>(qm, gkm, njm);
  compose_kernel<<<dim3(64, 2), 256, 0, stream>>>(njm, um);
  wqd_kernel<<<dim3(64, 2), 256, 0, stream>>>(um, dec_w, wqdcs);

  const int NB = (N_NODES + EPB - 1) / EPB;   // 469

  // two message-passing layers; node kernel emits the NEXT stage's P
  for (int l = 0; l < 2; ++l) {
    edge_mfma_kernel<<<N_EDGES / EB, 128, 0, stream>>>(
        Pbuf, rcp, era, cstart,
        e_w1 + (size_t)l * 258 * HDIM + 256 * HDIM,
        w2cs + (size_t)l * 4 * 4096, e_b2 + l * HDIM, agg, headp);
    node_mfma_kernel<<<NB, 256, 0, stream>>>(
        out, agg, cstart, cursor, headp,
        enccs + (size_t)l * 8 * 4096, enc_b + l * HDIM,
        wqdcs + (size_t)l * 4 * 4096, dec_b + l * HDIM,
        (l == 0) ? (w1cs + (size_t)9 * 4096) : cw1cs,
        (l == 0) ? (e_b1 + HDIM) : c_b1,
        Pbuf);
  }

  // coordinate head
  coord_mfma_kernel<<<N_EDGES / EB, 128, 0, stream>>>(
      Pbuf, rcp, era, x, c_w1 + 256 * HDIM, cw2cs, c_b2, c_w3,
      out + (size_t)N_NODES * HDIM);
}

// Round 11
// 658.993 us; speedup vs baseline: 1.1910x; 1.0604x over previous
//
#include <hip/hip_runtime.h>
#include <math.h>

#define N_NODES 30000
#define N_EDGES 480000
#define HDIM 128
#define EPB 64        // edges (or nodes) per MFMA tile; max node degree (~40)
                      // must be < EPB so a node's CSR range spans <=2 tiles.
#define NAS 264       // node A-tile row stride (bf16)
#define MS 136        // m1 / Ht row stride (bf16)
#define M2TS 72       // transposed m2 row stride (bf16): [128 cols][72]

typedef __attribute__((ext_vector_type(8))) short short8b;
typedef __attribute__((ext_vector_type(4))) float f32x4;

__device__ __forceinline__ float silu_f(float v) {
  return v / (1.0f + __expf(-v));
}

__device__ __forceinline__ unsigned short f2bf(float f) {
  unsigned int u = __float_as_uint(f);
  unsigned int r = u + 0x7fffu + ((u >> 16) & 1u);
  return (unsigned short)(r >> 16);
}

// HW packed f32->bf16 (RNE, same rounding as f2bf): 1 instr replaces ~9.
__device__ __forceinline__ unsigned int cvt_pk_bf16(float lo, float hi) {
  unsigned int r;
  asm("v_cvt_pk_bf16_f32 %0, %1, %2" : "=v"(r) : "v"(lo), "v"(hi));
  return r;
}

__device__ __forceinline__ ushort4 pk4(float4 v) {
  uint2 u;
  u.x = cvt_pk_bf16(v.x, v.y);
  u.y = cvt_pk_bf16(v.z, v.w);
  return *(ushort4*)&u;
}

// ---- fused init: out = [h | x], edge count histogram ------
__global__ void init_out_bf_kernel(const float* __restrict__ h,
                                   const float* __restrict__ x,
                                   const int* __restrict__ ei,
                                   float* __restrict__ out,
                                   int* __restrict__ cursor) {
  int idx = blockIdx.x * 256 + threadIdx.x;   // 960,000 float4 units
  ((float4*)out)[idx] = ((const float4*)h)[idx];
  if (idx < N_NODES * 3 / 4) {
    ((float4*)(out + N_NODES * HDIM))[idx] = ((const float4*)x)[idx];
  }
  if (idx < N_EDGES) atomicAdd(&cursor[ei[idx]], 1);
}

__global__ __launch_bounds__(1024) void scan_kernel(int* __restrict__ cursor,
                                                    int* __restrict__ cstart) {
  __shared__ int sums[1024];
  const int tid = threadIdx.x;
  const int base = tid * 30;
  int local[30];
  int s = 0;
#pragma unroll
  for (int j = 0; j < 30; ++j) {
    int idx = base + j;
    int d = (idx < N_NODES) ? cursor[idx] : 0;
    local[j] = s;
    s += d;
  }
  sums[tid] = s;
  __syncthreads();
  for (int off = 1; off < 1024; off <<= 1) {
    int add = (tid >= off) ? sums[tid - off] : 0;
    __syncthreads();
    sums[tid] += add;
    __syncthreads();
  }
  int excl = (tid == 0) ? 0 : sums[tid - 1];
#pragma unroll
  for (int j = 0; j < 30; ++j) {
    int idx = base + j;
    if (idx < N_NODES) {
      int v = excl + local[j];
      cursor[idx] = v;
      cstart[idx] = v;   // immutable CSR starts (cursor mutates in fill)
    }
  }
}

// ---- merged post-scan prep: fill | weight-convert | ns_init | gk | l0-P ---
// block ranges: 0-1874 fill (writes sorted rcp/era), 1875-2754 convert
// (55 chunks), 2755-3010 ns_init, 3011-3266 gk, 3267-3735 pgemm for layer 0.
__global__ void prep_kernel(
    const int* __restrict__ ei, int* __restrict__ cursor,
    unsigned int* __restrict__ rcp, float2* __restrict__ era,
    const float* __restrict__ x, const float* __restrict__ ea,
    const float* __restrict__ e_w1, const float* __restrict__ e_w2,
    const float* __restrict__ enc_w, const float* __restrict__ c_w1,
    const float* __restrict__ c_w2,
    ushort* __restrict__ w1cs, ushort* __restrict__ w2cs,
    ushort* __restrict__ enccs, ushort* __restrict__ cw1cs,
    ushort* __restrict__ cw2cs,
    const float* __restrict__ A_re, const float* __restrict__ A_im,
    float2* __restrict__ X,
    const float* __restrict__ coeffs, float2* __restrict__ gkm,
    const float* __restrict__ outh, const float* __restrict__ b1l0,
    ushort* __restrict__ P) {
  __shared__ ushort Ht[EPB * MS];   // used by the pgemm range only
  const int b = blockIdx.x, tid = threadIdx.x;
  if (b < 1875) {
    int e = b * 256 + tid;
    int r = ei[e];
    int c = ei[N_EDGES + e];
    int pos = atomicAdd(&cursor[r], 1);   // after: cursor[n] = CSR end
    rcp[pos] = (unsigned int)r | ((unsigned int)c << 16);
    float dx = x[r * 3 + 0] - x[c * 3 + 0];
    float dy = x[r * 3 + 1] - x[c * 3 + 1];
    float dz = x[r * 3 + 2] - x[c * 3 + 2];
    era[pos] = make_float2(dx * dx + dy * dy + dz * dz, ea[e]);
  } else if (b < 2755) {
    int idx = (b - 1875) * 256 + tid;     // 0 .. 225279 (= 55*4096)
    int ci = idx >> 12, rem = idx & 4095, kk = rem & 31;
    const float* W; ushort* dst; int Kreal, ktl;
    if (ci < 18) {
      int l = ci / 9; ktl = ci - l * 9;
      W = e_w1 + (size_t)l * 258 * HDIM; dst = w1cs + (size_t)l * 9 * 4096;
      Kreal = 258;
    } else if (ci < 26) {
      int c2 = ci - 18; int l = c2 >> 2; ktl = c2 & 3;
      W = e_w2 + (size_t)l * HDIM * HDIM; dst = w2cs + (size_t)l * 4 * 4096;
      Kreal = 128;
    } else if (ci < 42) {
      int c2 = ci - 26; int l = c2 >> 3; ktl = c2 & 7;
      W = enc_w + (size_t)l * 256 * HDIM; dst = enccs + (size_t)l * 8 * 4096;
      Kreal = 256;
    } else if (ci < 51) {
      ktl = ci - 42; W = c_w1; dst = cw1cs; Kreal = 258;
    } else {
      ktl = ci - 51; W = c_w2; dst = cw2cs; Kreal = 128;
    }
    int n = rem >> 5;
    int k = ktl * 32 + kk;
    float v = (k < Kreal) ? W[(size_t)k * HDIM + n] : 0.0f;
    dst[ktl * 4096 + rem] = f2bf(v);
  } else if (b < 3011) {
    int bb = b - 2755;
    int lj = bb >> 6;
    int idx = (bb & 63) * 256 + tid;
    int r = idx >> 7, c = idx & 127;
    const float* are = A_re + (size_t)lj * 16384;
    const float* aim = A_im + (size_t)lj * 16384;
    float re = are[r * 128 + c] + are[c * 128 + r];
    float im = aim[r * 128 + c] - aim[c * 128 + r];
    if (r == c) im -= 1.0f;
    X[(size_t)lj * 16384 + idx] = make_float2(re, im);
  } else if (b < 3267) {
    int bb = b - 3011;
    int lj = bb >> 6;
    float a = coeffs[lj * 2 + 0], bcf = coeffs[lj * 2 + 1];
    float ca = cosf(0.5f * a), sa = sinf(0.5f * a);
    float cb = cosf(0.5f * bcf), sb = sinf(0.5f * bcf);
    float2 G[2][2];
    G[0][0] = make_float2(cb * ca, sb * sa);
    G[0][1] = make_float2(-sb * ca, -cb * sa);
    G[1][0] = make_float2(sb * ca, -cb * sa);
    G[1][1] = make_float2(cb * ca, -sb * sa);
    int idx = (bb & 63) * 256 + tid;
    int r = idx >> 7, c = idx & 127;
    float2 acc = make_float2(1.f, 0.f);
#pragma unroll
    for (int bit = 6; bit >= 0; --bit) {
      float2 g = G[(r >> bit) & 1][(c >> bit) & 1];
      acc = make_float2(acc.x * g.x - acc.y * g.y, acc.x * g.y + acc.y * g.x);
    }
    gkm[(size_t)lj * 16384 + idx] = acc;
  } else {
    // ---- pgemm for layer 0: P = [h@W1r + b1 | h@W1c], staged from out ----
    const int n0 = (b - 3267) * EPB;
    const int lane = tid & 63, wave = tid >> 6;
    const int lrow = lane & 15, lq = lane >> 4;
    {
      const int e = tid >> 2, jj = tid & 3;
      int node = n0 + e;
      if (node >= N_NODES) node = N_NODES - 1;
      const float4* s4 = (const float4*)(outh + (size_t)node * HDIM + jj * 32);
      ushort* dst = Ht + e * MS + jj * 32;
#pragma unroll
      for (int i = 0; i < 8; ++i) {
        ((ushort4*)dst)[i] = pk4(s4[i]);
      }
    }
    short8b wf[4][4];
    const int cs = (wave >> 1) * 4;     // waves 0,1 -> W1r; 2,3 -> W1c
    const int nb = (wave & 1) * 64;
#pragma unroll
    for (int kt = 0; kt < 4; ++kt)
#pragma unroll
      for (int nt = 0; nt < 4; ++nt)
        wf[kt][nt] = *(const short8b*)(w1cs + (cs + kt) * 4096 + (nb + nt * 16 + lrow) * 32 + lq * 8);
    __syncthreads();

    f32x4 acc[4][4];
#pragma unroll
    for (int mt = 0; mt < 4; ++mt)
#pragma unroll
      for (int nt = 0; nt < 4; ++nt) acc[mt][nt] = (f32x4){0.f, 0.f, 0.f, 0.f};
#pragma unroll
    for (int kt = 0; kt < 4; ++kt) {
      short8b af[4];
#pragma unroll
      for (int mt = 0; mt < 4; ++mt)
        af[mt] = *(const short8b*)(Ht + (mt * 16 + lrow) * MS + kt * 32 + lq * 8);
#pragma unroll
      for (int mt = 0; mt < 4; ++mt)
#pragma unroll
        for (int nt = 0; nt < 4; ++nt)
          acc[mt][nt] = __builtin_amdgcn_mfma_f32_16x16x32_bf16(af[mt], wf[kt][nt], acc[mt][nt], 0, 0, 0);
    }
    const int cbase = wave * 64;
#pragma unroll
    for (int nt = 0; nt < 4; ++nt) {
      const int ccol = cbase + nt * 16 + lrow;
      const float bb2 = (ccol < 128) ? b1l0[ccol] : 0.f;
#pragma unroll
      for (int mt = 0; mt < 4; ++mt)
#pragma unroll
        for (int r = 0; r < 4; ++r) {
          const int node = n0 + mt * 16 + lq * 4 + r;
          if (node < N_NODES) P[(size_t)node * 256 + ccol] = f2bf(acc[mt][nt][r] + bb2);
        }
    }
  }
}

// ============ Newton-Schulz inverse of B = A_h + iI (2 iterations) ========
__global__ void ns_bx_kernel(const float* __restrict__ Are,
                             const float* __restrict__ Aim,
                             const float2* __restrict__ X,
                             float2* __restrict__ T) {
  int lj = blockIdx.y;
  int idx = blockIdx.x * 256 + threadIdx.x;
  int r = idx >> 7, c = idx & 127;
  const float* are = Are + (size_t)lj * 16384;
  const float* aim = Aim + (size_t)lj * 16384;
  const float2* x = X + (size_t)lj * 16384;
  float2 acc = make_float2(0.f, 0.f);
  for (int k = 0; k < 128; ++k) {
    float re = are[r * 128 + k] + are[k * 128 + r];
    float im = aim[r * 128 + k] - aim[k * 128 + r];
    if (k == r) im += 1.0f;
    float2 b = x[k * 128 + c];
    acc.x += re * b.x - im * b.y;
    acc.y += re * b.y + im * b.x;
  }
  T[(size_t)lj * 16384 + idx] = acc;
}

__global__ void ns_upd_kernel(const float2* __restrict__ X,
                              const float2* __restrict__ T,
                              float2* __restrict__ Xn) {
  int lj = blockIdx.y;
  int idx = blockIdx.x * 256 + threadIdx.x;
  int r = idx >> 7, c = idx & 127;
  const float2* x = X + (size_t)lj * 16384;
  const float2* t = T + (size_t)lj * 16384;
  float2 acc = make_float2(0.f, 0.f);
  for (int k = 0; k < 128; ++k) {
    float2 a = x[r * 128 + k];
    float2 b = t[k * 128 + c];
    acc.x += a.x * b.x - a.y * b.y;
    acc.y += a.x * b.y + a.y * b.x;
  }
  float2 xc = x[r * 128 + c];
  Xn[(size_t)lj * 16384 + idx] = make_float2(2.f * xc.x - acc.x, 2.f * xc.y - acc.y);
}

// ---------------- q = (A_h - iI) * Binv ----------------
__global__ void qmat_kernel(const float* __restrict__ Are,
                            const float* __restrict__ Aim,
                            const float2* __restrict__ binvg,
                            float2* __restrict__ qm) {
  int lj = blockIdx.y;
  int idx = blockIdx.x * 256 + threadIdx.x;
  int r = idx >> 7, c = idx & 127;
  const float* are = Are + (size_t)lj * 16384;
  const float* aim = Aim + (size_t)lj * 16384;
  const float2* binv = binvg + (size_t)lj * 16384;
  float2 acc = make_float2(0.f, 0.f);
  for (int k = 0; k < 128; ++k) {
    float re = are[r * 128 + k] + are[k * 128 + r];
    float im = aim[r * 128 + k] - aim[k * 128 + r];
    if (k == r) im -= 1.0f;
    float2 b = binv[k * 128 + c];
    acc.x += re * b.x - im * b.y;
    acc.y += re * b.y + im * b.x;
  }
  qm[(size_t)lj * 16384 + idx] = acc;
}

// ------- N_j[i][c] = sum_k q[k][i] * Gk[g[c]][k]  (CNOT perm inlined) ------
__global__ void nj_kernel(const float2* __restrict__ qm,
                          const float2* __restrict__ gkm,
                          float2* __restrict__ njm) {
  int lj = blockIdx.y;
  int idx = blockIdx.x * 256 + threadIdx.x;
  int i = idx >> 7, c = idx & 127;
  int gc;
  {
    int v = c;
    const int cs[7] = {6, 5, 4, 3, 2, 1, 0};
    const int ts[7] = {0, 6, 5, 4, 3, 2, 1};
#pragma unroll
    for (int p = 0; p < 7; ++p) {
      int cb = (v >> (6 - cs[p])) & 1;
      v = v ^ (cb << (6 - ts[p]));
    }
    gc = v;
  }
  const float2* q = qm + (size_t)lj * 16384;
  const float2* gk = gkm + (size_t)lj * 16384;
  float2 acc = make_float2(0.f, 0.f);
  for (int k = 0; k < 128; ++k) {
    float2 qa = q[k * 128 + i];
    float2 gb = gk[gc * 128 + k];
    acc.x += qa.x * gb.x - qa.y * gb.y;
    acc.y += qa.x * gb.y + qa.y * gb.x;
  }
  njm[(size_t)lj * 16384 + idx] = acc;
}

// ---------------- U_l = N_{l,0} @ N_{l,1} ----------------
__global__ void compose_kernel(const float2* __restrict__ njm,
                               float2* __restrict__ um) {
  int l = blockIdx.y;
  int idx = blockIdx.x * 256 + threadIdx.x;
  int i = idx >> 7, c = idx & 127;
  const float2* n0 = njm + (size_t)(l * 2 + 0) * 16384;
  const float2* n1 = njm + (size_t)(l * 2 + 1) * 16384;
  float2 acc = make_float2(0.f, 0.f);
  for (int k = 0; k < 128; ++k) {
    float2 a = n0[i * 128 + k];
    float2 b = n1[k * 128 + c];
    acc.x += a.x * b.x - a.y * b.y;
    acc.y += a.x * b.y + a.y * b.x;
  }
  um[(size_t)l * 16384 + idx] = acc;
}

// -------- Wqd_l = Re(U_l) @ dec_w_l, written DIRECTLY as bf16 chunks -------
__global__ void wqd_kernel(const float2* __restrict__ um,
                           const float* __restrict__ decw,
                           ushort* __restrict__ wqdcs) {
  int l = blockIdx.y;
  int idx = blockIdx.x * 256 + threadIdx.x;
  int i = idx >> 7, c = idx & 127;     // i = k-dim (D), c = n-dim (H)
  const float2* u = um + (size_t)l * 16384;
  const float* dw = decw + (size_t)l * 16384;
  float acc = 0.f;
  for (int k = 0; k < 128; ++k) acc += u[i * 128 + k].x * dw[k * 128 + c];
  wqdcs[(size_t)l * 4 * 4096 + (i >> 5) * 4096 + c * 32 + (i & 31)] = f2bf(acc);
}

// ==================== edge MLP: P-gather + combine + GEMM2 + MFMA reduce ===
// Best-verified configuration (round 8, 664.6 us total): EPB=64 / 256
// threads; m2t write packed via cvt_pk + b64 store; indicator GEMM
// per-16-seg-group compute->scatter (8 live accs).
__global__ __launch_bounds__(256, 4) void edge_mfma_kernel(
    const ushort* __restrict__ P, const unsigned int* __restrict__ rcp,
    const float2* __restrict__ era, const int* __restrict__ cstart,
    const float* __restrict__ wm,      // f32: [0:128]=radial row, [128:256]=ea row
    const ushort* __restrict__ w2cs, const float* __restrict__ b2,
    float* __restrict__ agg, float* __restrict__ headp) {
  __shared__ ushort buf[128 * M2TS];     // m1 (64x136=8704) / m2t (9216) overlay
  __shared__ int rows[EPB];
  __shared__ __align__(16) ushort segv[EPB];
  __shared__ int segnode[EPB];
  __shared__ int scont, snseg;
  ushort* m1 = buf;
  ushort* m2t = buf;

  const int tid = threadIdx.x;
  const int lane = tid & 63, wave = tid >> 6;
  const int lrow = lane & 15, lq = lane >> 4;
  const int wbase = wave * 32;
  const int woff0 = (wbase + lrow) * 32 + lq * 8;
  const int woff1 = (wbase + 16 + lrow) * 32 + lq * 8;
  const float b2v[2] = {b2[wbase + lrow], b2[wbase + 16 + lrow]};

  const int i0 = blockIdx.x * EPB;
  {
    const int e = tid >> 2, j = tid & 3;
    const unsigned int rcv = rcp[i0 + e];
    const int r = (int)(rcv & 0xFFFFu), c = (int)(rcv >> 16);
    if (j == 0) rows[e] = r;
    const float2 re2 = era[i0 + e];
    const float radial = re2.x, eav = re2.y;
    const uint4* pr = (const uint4*)(P + (size_t)r * 256 + j * 32);
    const uint4* pc = (const uint4*)(P + (size_t)c * 256 + 128 + j * 32);
    uint4 PR[4] = {pr[0], pr[1], pr[2], pr[3]};
    uint4 PC[4] = {pc[0], pc[1], pc[2], pc[3]};
#pragma unroll
    for (int q = 0; q < 4; ++q) {
      const int kb = j * 32 + q * 8;
      const uint ua[4] = {PR[q].x, PR[q].y, PR[q].z, PR[q].w};
      const uint ub[4] = {PC[q].x, PC[q].y, PC[q].z, PC[q].w};
      uint ow[4];
#pragma unroll
      for (int w = 0; w < 4; ++w) {
        const int k = kb + w * 2;
        float v0 = __uint_as_float(ua[w] << 16) + __uint_as_float(ub[w] << 16)
                 + radial * wm[k] + eav * wm[128 + k];
        float v1 = __uint_as_float(ua[w] & 0xffff0000u) + __uint_as_float(ub[w] & 0xffff0000u)
                 + radial * wm[k + 1] + eav * wm[129 + k];
        ow[w] = cvt_pk_bf16(silu_f(v0), silu_f(v1));
      }
      uint4 o; o.x = ow[0]; o.y = ow[1]; o.z = ow[2]; o.w = ow[3];
      *(uint4*)(m1 + e * MS + kb) = o;
    }
  }
  __syncthreads();   // s1: m1 ready

  f32x4 acc2[4][2];
#pragma unroll
  for (int mt = 0; mt < 4; ++mt)
#pragma unroll
    for (int nt = 0; nt < 2; ++nt) acc2[mt][nt] = (f32x4){0.f, 0.f, 0.f, 0.f};
  {
    short8b wcur0 = *(const short8b*)(w2cs + woff0);
    short8b wcur1 = *(const short8b*)(w2cs + woff1);
#pragma unroll
    for (int kt = 0; kt < 4; ++kt) {
      short8b wn0, wn1;
      if (kt < 3) {
        wn0 = *(const short8b*)(w2cs + (kt + 1) * 4096 + woff0);
        wn1 = *(const short8b*)(w2cs + (kt + 1) * 4096 + woff1);
      }
      short8b af[4];
#pragma unroll
      for (int mt = 0; mt < 4; ++mt)
        af[mt] = *(const short8b*)(m1 + (mt * 16 + lrow) * MS + kt * 32 + lq * 8);
#pragma unroll
      for (int mt = 0; mt < 4; ++mt) {
        acc2[mt][0] = __builtin_amdgcn_mfma_f32_16x16x32_bf16(af[mt], wcur0, acc2[mt][0], 0, 0, 0);
        acc2[mt][1] = __builtin_amdgcn_mfma_f32_16x16x32_bf16(af[mt], wcur1, acc2[mt][1], 0, 0, 0);
      }
      if (kt < 3) { wcur0 = wn0; wcur1 = wn1; }
    }
  }
  __syncthreads();   // s2: all m1 reads done (m2t overlays)

  // m2 (bf16, transposed [col][edge]) written PACKED: for fixed (mt,nt) the
  // four r-values are consecutive e -> 2 cvt_pk + one b64 store.
#pragma unroll
  for (int mt = 0; mt < 4; ++mt)
#pragma unroll
    for (int nt = 0; nt < 2; ++nt) {
      const int col = wbase + nt * 16 + lrow;
      uint2 u;
      u.x = cvt_pk_bf16(silu_f(acc2[mt][nt][0] + b2v[nt]),
                        silu_f(acc2[mt][nt][1] + b2v[nt]));
      u.y = cvt_pk_bf16(silu_f(acc2[mt][nt][2] + b2v[nt]),
                        silu_f(acc2[mt][nt][3] + b2v[nt]));
      *(uint2*)(m2t + col * M2TS + mt * 16 + lq * 4) = u;
    }
  if (wave == 0) {
    const int e = lane;
    const int re_ = rows[e];
    const bool leader = (e == 0) || (rows[e - 1] != re_);
    const unsigned long long mask = __ballot(leader);
    const int seg = (int)__popcll(mask & ((1ull << e) - 1ull));
    segv[e] = (ushort)seg;
    if (leader) segnode[seg] = re_;
    if (e == 0) {
      snseg = (int)__popcll(mask);
      scont = (cstart[re_] < i0) ? 1 : 0;
    }
  }
  __syncthreads();   // s3: m2t + seg ready

  // indicator GEMM: OUT[m2col][seg] = sum_e m2t[m2col][e] * (segv[e]==seg)
  // per-16-seg-group compute -> scatter (block-uniform trip count, 8 live accs)
  const int nseg = snseg, cont = scont;
  const int ntmax = (nseg + 15) >> 4;     // usually 1 (avg ~5 segs/block)
  const short8b sv0 = *(const short8b*)(segv + lq * 8);
  const short8b sv1 = *(const short8b*)(segv + 32 + lq * 8);
  const int mtb = wave * 32;
  short8b afr[2][2];
#pragma unroll
  for (int mt = 0; mt < 2; ++mt) {
    const ushort* rp = m2t + (mtb + mt * 16 + lrow) * M2TS + lq * 8;
    afr[mt][0] = *(const short8b*)(rp);
    afr[mt][1] = *(const short8b*)(rp + 32);
  }
  for (int nt = 0; nt < ntmax; ++nt) {    // block-uniform
    const int tgt = nt * 16 + lrow;
    uint p0[4], p1[4];
#pragma unroll
    for (int w = 0; w < 4; ++w) {
      p0[w] = (((int)(ushort)sv0[2 * w] == tgt) ? 0x3F80u : 0u)
            | (((int)(ushort)sv0[2 * w + 1] == tgt) ? 0x3F800000u : 0u);
      p1[w] = (((int)(ushort)sv1[2 * w] == tgt) ? 0x3F80u : 0u)
            | (((int)(ushort)sv1[2 * w + 1] == tgt) ? 0x3F800000u : 0u);
    }
    uint4 u0 = make_uint4(p0[0], p0[1], p0[2], p0[3]);
    uint4 u1 = make_uint4(p1[0], p1[1], p1[2], p1[3]);
    const short8b bf0 = *(const short8b*)&u0;
    const short8b bf1 = *(const short8b*)&u1;
    f32x4 r0 = (f32x4){0.f, 0.f, 0.f, 0.f};
    f32x4 r1 = (f32x4){0.f, 0.f, 0.f, 0.f};
    r0 = __builtin_amdgcn_mfma_f32_16x16x32_bf16(afr[0][0], bf0, r0, 0, 0, 0);
    r0 = __builtin_amdgcn_mfma_f32_16x16x32_bf16(afr[0][1], bf1, r0, 0, 0, 0);
    r1 = __builtin_amdgcn_mfma_f32_16x16x32_bf16(afr[1][0], bf0, r1, 0, 0, 0);
    r1 = __builtin_amdgcn_mfma_f32_16x16x32_bf16(afr[1][1], bf1, r1, 0, 0, 0);
    const int seg = tgt;
    if (seg < nseg) {
      const int node = segnode[seg];
      float* dst = (seg == 0 && cont) ? (headp + (size_t)blockIdx.x * HDIM)
                                      : (agg + (size_t)node * HDIM);
#pragma unroll
      for (int r = 0; r < 4; ++r) {
        dst[mtb + lq * 4 + r] = r0[r];
        dst[mtb + 16 + lq * 4 + r] = r1[r];
      }
    }
  }
}

// ==================== MFMA node update (folds headp, emits next-layer P) ===
__global__ __launch_bounds__(256, 2) void node_mfma_kernel(
    float* __restrict__ out_h, const float* __restrict__ agg,
    const int* __restrict__ cstart, const int* __restrict__ cend,
    const float* __restrict__ headp,
    const ushort* __restrict__ enccs, const float* __restrict__ encb,
    const ushort* __restrict__ wqdcs, const float* __restrict__ decb,
    const ushort* __restrict__ w1n, const float* __restrict__ b1n,
    ushort* __restrict__ Pout) {
  __shared__ ushort A[EPB * NAS];
  __shared__ ushort m1[EPB * MS];
  __shared__ float nbuf[4 * EPB];
  const int tid = threadIdx.x;
  const int n0 = blockIdx.x * EPB;

  const int lane = tid & 63, wave = tid >> 6;
  const int lrow = lane & 15, lq = lane >> 4;
  const int wbase = wave * 32;

  short8b wef[8][2], wqf[4][2];
#pragma unroll
  for (int kt = 0; kt < 8; ++kt)
#pragma unroll
    for (int nt = 0; nt < 2; ++nt)
      wef[kt][nt] = *(const short8b*)(enccs + kt * 4096 + (wbase + nt * 16 + lrow) * 32 + lq * 8);
#pragma unroll
  for (int kt = 0; kt < 4; ++kt)
#pragma unroll
    for (int nt = 0; nt < 2; ++nt)
      wqf[kt][nt] = *(const short8b*)(wqdcs + kt * 4096 + (wbase + nt * 16 + lrow) * 32 + lq * 8);
  const float ebv[2] = {encb[wbase + lrow], encb[wbase + 16 + lrow]};
  const float dbv[2] = {decb[wbase + lrow], decb[wbase + 16 + lrow]};

  {
    const int e = tid >> 2, j = tid & 3;
    int node = n0 + e;
    if (node >= N_NODES) node = N_NODES - 1;
    if (j < 2) {
      const float4* s4 = (const float4*)(out_h + (size_t)node * HDIM + j * 64);
      ushort* dst = A + e * NAS + j * 64;
#pragma unroll
      for (int i = 0; i < 16; ++i) {
        ((ushort4*)dst)[i] = pk4(s4[i]);
      }
    } else {
      const int s = cstart[node], en = cend[node];
      const bool hasAgg = en > s;
      const float4* a4 = (const float4*)(agg + (size_t)node * HDIM + (j - 2) * 64);
      const int bb0 = (s >> 6) + 1;
      const int bb1 = hasAgg ? ((en - 1) >> 6) : 0;
      ushort* dst = A + e * NAS + 128 + (j - 2) * 64;
#pragma unroll
      for (int i = 0; i < 16; ++i) {
        float4 v = hasAgg ? a4[i] : make_float4(0.f, 0.f, 0.f, 0.f);
        for (int bb = bb0; bb <= bb1; ++bb) {
          float4 hv = *(const float4*)(headp + (size_t)bb * HDIM + (j - 2) * 64 + i * 4);
          v.x += hv.x; v.y += hv.y; v.z += hv.z; v.w += hv.w;
        }
        float4 sv = make_float4(v.x * 0.01f, v.y * 0.01f, v.z * 0.01f, v.w * 0.01f);
        ((ushort4*)dst)[i] = pk4(sv);
      }
    }
  }
  __syncthreads();

  f32x4 acc[4][2];
#pragma unroll
  for (int mt = 0; mt < 4; ++mt)
#pragma unroll
    for (int nt = 0; nt < 2; ++nt) acc[mt][nt] = (f32x4){0.f, 0.f, 0.f, 0.f};
#pragma unroll
  for (int kt = 0; kt < 8; ++kt) {
    short8b af[4];
#pragma unroll
    for (int mt = 0; mt < 4; ++mt)
      af[mt] = *(const short8b*)(A + (mt * 16 + lrow) * NAS + kt * 32 + lq * 8);
#pragma unroll
    for (int mt = 0; mt < 4; ++mt)
#pragma unroll
      for (int nt = 0; nt < 2; ++nt)
        acc[mt][nt] = __builtin_amdgcn_mfma_f32_16x16x32_bf16(af[mt], wef[kt][nt], acc[mt][nt], 0, 0, 0);
  }
#pragma unroll
  for (int mt = 0; mt < 4; ++mt) {
    float ssp[4] = {0.f, 0.f, 0.f, 0.f};
#pragma unroll
    for (int nt = 0; nt < 2; ++nt)
#pragma unroll
      for (int r = 0; r < 4; ++r) {
        acc[mt][nt][r] += ebv[nt];
        ssp[r] += acc[mt][nt][r] * acc[mt][nt][r];
      }
#pragma unroll
    for (int m = 1; m < 16; m <<= 1)
#pragma unroll
      for (int r = 0; r < 4; ++r) ssp[r] += __shfl_xor(ssp[r], m, 64);
    if (lrow == 0) {
#pragma unroll
      for (int r = 0; r < 4; ++r)
        nbuf[wave * EPB + mt * 16 + lq * 4 + r] = ssp[r];
    }
  }
  __syncthreads();
#pragma unroll
  for (int mt = 0; mt < 4; ++mt)
#pragma unroll
    for (int r = 0; r < 4; ++r) {
      const int row = mt * 16 + lq * 4 + r;
      float sum = nbuf[row] + nbuf[EPB + row] + nbuf[2 * EPB + row] + nbuf[3 * EPB + row];
      float inv = 1.0f / sqrtf(sum + 1e-12f);
#pragma unroll
      for (int nt = 0; nt < 2; ++nt)
        m1[row * MS + wbase + nt * 16 + lrow] = f2bf(acc[mt][nt][r] * inv);
    }
  __syncthreads();

  f32x4 acc2[4][2];
#pragma unroll
  for (int mt = 0; mt < 4; ++mt)
#pragma unroll
    for (int nt = 0; nt < 2; ++nt) acc2[mt][nt] = (f32x4){0.f, 0.f, 0.f, 0.f};
#pragma unroll
  for (int kt = 0; kt < 4; ++kt) {
    short8b af[4];
#pragma unroll
    for (int mt = 0; mt < 4; ++mt)
      af[mt] = *(const short8b*)(m1 + (mt * 16 + lrow) * MS + kt * 32 + lq * 8);
#pragma unroll
    for (int mt = 0; mt < 4; ++mt)
#pragma unroll
      for (int nt = 0; nt < 2; ++nt)
        acc2[mt][nt] = __builtin_amdgcn_mfma_f32_16x16x32_bf16(af[mt], wqf[kt][nt], acc2[mt][nt], 0, 0, 0);
  }
  __syncthreads();   // all m1 (normed q) reads done; m1 will hold hn (bf16)

  // ---- h += dec(qs) + dec_b; stash hn bf16 to m1 for the next-P GEMM ----
#pragma unroll
  for (int mt = 0; mt < 4; ++mt)
#pragma unroll
    for (int nt = 0; nt < 2; ++nt) {
      const int n = wbase + nt * 16 + lrow;
#pragma unroll
      for (int r = 0; r < 4; ++r) {
        const int node = n0 + mt * 16 + lq * 4 + r;
        float hn = 0.f;
        if (node < N_NODES) {
          size_t off = (size_t)node * HDIM + n;
          hn = out_h[off] + acc2[mt][nt][r] + dbv[nt];
          out_h[off] = hn;
        }
        m1[(mt * 16 + lq * 4 + r) * MS + n] = f2bf(hn);
      }
    }
  __syncthreads();   // hn tile ready

  // ---- next-stage P: P[node] = [hn@W1r + b1n | hn@W1c] (pgemm structure) --
  short8b wfp[4][4];
  const int csn = (wave >> 1) * 4;
  const int nbw = (wave & 1) * 64;
#pragma unroll
  for (int kt = 0; kt < 4; ++kt)
#pragma unroll
    for (int nt = 0; nt < 4; ++nt)
      wfp[kt][nt] = *(const short8b*)(w1n + (csn + kt) * 4096 + (nbw + nt * 16 + lrow) * 32 + lq * 8);
  f32x4 pacc[4][4];
#pragma unroll
  for (int mt = 0; mt < 4; ++mt)
#pragma unroll
    for (int nt = 0; nt < 4; ++nt) pacc[mt][nt] = (f32x4){0.f, 0.f, 0.f, 0.f};
#pragma unroll
  for (int kt = 0; kt < 4; ++kt) {
    short8b af[4];
#pragma unroll
    for (int mt = 0; mt < 4; ++mt)
      af[mt] = *(const short8b*)(m1 + (mt * 16 + lrow) * MS + kt * 32 + lq * 8);
#pragma unroll
    for (int mt = 0; mt < 4; ++mt)
#pragma unroll
      for (int nt = 0; nt < 4; ++nt)
        pacc[mt][nt] = __builtin_amdgcn_mfma_f32_16x16x32_bf16(af[mt], wfp[kt][nt], pacc[mt][nt], 0, 0, 0);
  }
  const int cbase = wave * 64;
#pragma unroll
  for (int nt = 0; nt < 4; ++nt) {
    const int ccol = cbase + nt * 16 + lrow;
    const float bb2 = (ccol < 128) ? b1n[ccol] : 0.f;
#pragma unroll
    for (int mt = 0; mt < 4; ++mt)
#pragma unroll
      for (int r = 0; r < 4; ++r) {
        const int node = n0 + mt * 16 + lq * 4 + r;
        if (node < N_NODES) Pout[(size_t)node * 256 + ccol] = f2bf(pacc[mt][nt][r] + bb2);
      }
  }
}

// ==================== coordinate head: P-gather + combine + GEMM2 ==========
__global__ __launch_bounds__(256, 4) void coord_mfma_kernel(
    const ushort* __restrict__ P, const unsigned int* __restrict__ rcp,
    const float2* __restrict__ era, const float* __restrict__ x,
    const float* __restrict__ wm,      // c_w1 rows 256,257 (f32)
    const ushort* __restrict__ w2cs, const float* __restrict__ b2,
    const float* __restrict__ w3, float* __restrict__ xout) {
  __shared__ ushort m1[EPB * MS];
  __shared__ int rows[EPB];
  __shared__ float pbuf[4 * EPB];
  __shared__ float tv[EPB];
  __shared__ float dxs[EPB], dys[EPB], dzs[EPB], ses[EPB];

  const int tid = threadIdx.x;
  const int lane = tid & 63, wave = tid >> 6;
  const int lrow = lane & 15, lq = lane >> 4;
  const int wbase = wave * 32;
  const int woff0 = (wbase + lrow) * 32 + lq * 8;
  const int woff1 = (wbase + 16 + lrow) * 32 + lq * 8;

  const float b2v[2] = {b2[wbase + lrow], b2[wbase + 16 + lrow]};
  const float w3v[2] = {w3[wbase + lrow], w3[wbase + 16 + lrow]};

  const int i0 = blockIdx.x * EPB;
  {
    const int e = tid >> 2, j = tid & 3;
    const unsigned int rcv = rcp[i0 + e];
    const int r = (int)(rcv & 0xFFFFu), c = (int)(rcv >> 16);
    if (j == 0) rows[e] = r;
    const float2 re2 = era[i0 + e];
    const float radial = re2.x, eav = re2.y;
    const uint4* pr = (const uint4*)(P + (size_t)r * 256 + j * 32);
    const uint4* pc = (const uint4*)(P + (size_t)c * 256 + 128 + j * 32);
    uint4 PR[4] = {pr[0], pr[1], pr[2], pr[3]};
    uint4 PC[4] = {pc[0], pc[1], pc[2], pc[3]};
    if (j == 3) {
      float dx = x[r * 3 + 0] - x[c * 3 + 0];
      float dy = x[r * 3 + 1] - x[c * 3 + 1];
      float dz = x[r * 3 + 2] - x[c * 3 + 2];
      dxs[e] = dx; dys[e] = dy; dzs[e] = dz;
      ses[e] = 1.0f / (sqrtf(radial + 1e-8f) + 1.0f);
    }
#pragma unroll
    for (int q = 0; q < 4; ++q) {
      const int kb = j * 32 + q * 8;
      const uint ua[4] = {PR[q].x, PR[q].y, PR[q].z, PR[q].w};
      const uint ub[4] = {PC[q].x, PC[q].y, PC[q].z, PC[q].w};
      uint ow[4];
#pragma unroll
      for (int w = 0; w < 4; ++w) {
        const int k = kb + w * 2;
        float v0 = __uint_as_float(ua[w] << 16) + __uint_as_float(ub[w] << 16)
                 + radial * wm[k] + eav * wm[128 + k];
        float v1 = __uint_as_float(ua[w] & 0xffff0000u) + __uint_as_float(ub[w] & 0xffff0000u)
                 + radial * wm[k + 1] + eav * wm[129 + k];
        ow[w] = cvt_pk_bf16(silu_f(v0), silu_f(v1));
      }
      uint4 o; o.x = ow[0]; o.y = ow[1]; o.z = ow[2]; o.w = ow[3];
      *(uint4*)(m1 + e * MS + kb) = o;
    }
  }
  __syncthreads();   // s1: m1 ready

  f32x4 acc2[4][2];
#pragma unroll
  for (int mt = 0; mt < 4; ++mt)
#pragma unroll
    for (int nt = 0; nt < 2; ++nt) acc2[mt][nt] = (f32x4){0.f, 0.f, 0.f, 0.f};
  {
    short8b wcur0 = *(const short8b*)(w2cs + woff0);
    short8b wcur1 = *(const short8b*)(w2cs + woff1);
#pragma unroll
    for (int kt = 0; kt < 4; ++kt) {
      short8b wn0, wn1;
      if (kt < 3) {
        wn0 = *(const short8b*)(w2cs + (kt + 1) * 4096 + woff0);
        wn1 = *(const short8b*)(w2cs + (kt + 1) * 4096 + woff1);
      }
      short8b af[4];
#pragma unroll
      for (int mt = 0; mt < 4; ++mt)
        af[mt] = *(const short8b*)(m1 + (mt * 16 + lrow) * MS + kt * 32 + lq * 8);
#pragma unroll
      for (int mt = 0; mt < 4; ++mt) {
        acc2[mt][0] = __builtin_amdgcn_mfma_f32_16x16x32_bf16(af[mt], wcur0, acc2[mt][0], 0, 0, 0);
        acc2[mt][1] = __builtin_amdgcn_mfma_f32_16x16x32_bf16(af[mt], wcur1, acc2[mt][1], 0, 0, 0);
      }
      if (kt < 3) { wcur0 = wn0; wcur1 = wn1; }
    }
  }
#pragma unroll
  for (int mt = 0; mt < 4; ++mt) {
    float p[4] = {0.f, 0.f, 0.f, 0.f};
#pragma unroll
    for (int nt = 0; nt < 2; ++nt)
#pragma unroll
      for (int r = 0; r < 4; ++r)
        p[r] += silu_f(acc2[mt][nt][r] + b2v[nt]) * w3v[nt];
#pragma unroll
    for (int m = 1; m < 16; m <<= 1)
#pragma unroll
      for (int r = 0; r < 4; ++r) p[r] += __shfl_xor(p[r], m, 64);
    if (lrow == 0) {
#pragma unroll
      for (int r = 0; r < 4; ++r)
        pbuf[wave * EPB + mt * 16 + lq * 4 + r] = p[r];
    }
  }
  __syncthreads();   // s2
  if (tid < EPB) {
    tv[tid] = (pbuf[tid] + pbuf[EPB + tid] + pbuf[2 * EPB + tid] + pbuf[3 * EPB + tid])
              * 0.01f * ses[tid];
  }
  __syncthreads();   // s3: tv ready
  if (tid < EPB) {
    const int e = tid;
    const int r_e = rows[e];
    const bool leader = (e == 0) || (rows[e - 1] != r_e);
    if (leader) {
      float sx = 0.f, sy = 0.f, sz = 0.f;
      int f = e;
      do {
        float t = tv[f];
        sx += dxs[f] * t; sy += dys[f] * t; sz += dzs[f] * t;
        ++f;
      } while (f < EPB && rows[f] == r_e);
      atomicAdd(&xout[r_e * 3 + 0], sx);
      atomicAdd(&xout[r_e * 3 + 1], sy);
      atomicAdd(&xout[r_e * 3 + 2], sz);
    }
  }
}

extern "C" void kernel_launch(void* const* d_in, const int* in_sizes, int n_in,
                              void* d_out, int out_size, void* d_ws, size_t ws_size,
                              hipStream_t stream) {
  const float* h     = (const float*)d_in[0];
  const float* x     = (const float*)d_in[1];
  const int*   ei    = (const int*)d_in[2];
  const float* ea    = (const float*)d_in[3];
  const float* e_w1  = (const float*)d_in[4];
  const float* e_b1  = (const float*)d_in[5];
  const float* e_w2  = (const float*)d_in[6];
  const float* e_b2  = (const float*)d_in[7];
  const float* enc_w = (const float*)d_in[8];
  const float* enc_b = (const float*)d_in[9];
  const float* coeffs= (const float*)d_in[10];
  const float* A_re  = (const float*)d_in[11];
  const float* A_im  = (const float*)d_in[12];
  const float* dec_w = (const float*)d_in[13];
  const float* dec_b = (const float*)d_in[14];
  const float* c_w1  = (const float*)d_in[15];
  const float* c_b1  = (const float*)d_in[16];
  const float* c_w2  = (const float*)d_in[17];
  const float* c_b2  = (const float*)d_in[18];
  const float* c_w3  = (const float*)d_in[19];

  float* out = (float*)d_out;
  float* ws  = (float*)d_ws;

  // workspace layout (float offsets) — ~44.6 MB
  float*        agg    = ws;                          // 3,840,000
  float2*       xa     = (float2*)(ws + 3840000);     // 131,072 f
  float2*       xb     = (float2*)(ws + 3971072);     // 131,072 f
  float2*       xt     = (float2*)(ws + 4102144);     // 131,072 f
  float2*       qm     = (float2*)(ws + 4233216);     // 131,072 f
  float2*       gkm    = (float2*)(ws + 4364288);     // 131,072 f
  float2*       njm    = (float2*)(ws + 4495360);     // 131,072 f
  float2*       um     = (float2*)(ws + 4626432);     //  65,536 f
  int*          cursor = (int*)(ws + 4724864);        //  30,000 (post-fill: CSR ends)
  int*          cstart = (int*)(ws + 4754864);        //  30,000 (CSR starts)
  unsigned int* rcp    = (unsigned int*)(ws + 4784864); // 480,000 (r | c<<16, sorted)
  float2*       era    = (float2*)(ws + 5264864);     // 480,000 f2 = 960,000 f
  float*        headp  = ws + 6224864;                // 7500*128 = 960,000
  ushort*       w1cs   = (ushort*)(ws + 7184864);     // 36,864 f
  ushort*       w2cs   = (ushort*)(ws + 7221728);     // 16,384 f
  ushort*       cw1cs  = (ushort*)(ws + 7238112);     // 18,432 f
  ushort*       cw2cs  = (ushort*)(ws + 7256544);     //  8,192 f
  ushort*       enccs  = (ushort*)(ws + 7264736);     // 32,768 f
  ushort*       wqdcs  = (ushort*)(ws + 7297504);     // 16,384 f
  ushort*       Pbuf   = (ushort*)(ws + 7313888);     // 30000*256 bf16 = 3,840,000 f

  // init: out=[h|x], count histogram (cursor pre-zeroed)
  hipMemsetAsync(cursor, 0, N_NODES * sizeof(int), stream);
  init_out_bf_kernel<<<3750, 256, 0, stream>>>(h, x, ei, out, cursor);
  scan_kernel<<<1, 1024, 0, stream>>>(cursor, cstart);

  // merged prep: fill(rcp/era) + weight converts + ns_init + gk + layer0-P
  prep_kernel<<<3736, 256, 0, stream>>>(ei, cursor, rcp, era, x, ea,
                                        e_w1, e_w2, enc_w, c_w1, c_w2,
                                        w1cs, w2cs, enccs, cw1cs, cw2cs,
                                        A_re, A_im, xa, coeffs, gkm,
                                        out, e_b1, Pbuf);

  // Newton-Schulz (2 iterations) + tiny GEMM chain
  float2* cur = xa;
  float2* nxt = xb;
  for (int it = 0; it < 2; ++it) {
    ns_bx_kernel<<<dim3(64, 4), 256, 0, stream>>>(A_re, A_im, cur, xt);
    ns_upd_kernel<<<dim3(64, 4), 256, 0, stream>>>(cur, xt, nxt);
    float2* tmp = cur; cur = nxt; nxt = tmp;
  }
  qmat_kernel<<<dim3(64, 4), 256, 0, stream>>>(A_re, A_im, cur, qm);
  nj_kernel<<<dim3(64, 4), 256, 0, stream>>>(qm, gkm, njm);
  compose_kernel<<<dim3(64, 2), 256, 0, stream>>>(njm, um);
  wqd_kernel<<<dim3(64, 2), 256, 0, stream>>>(um, dec_w, wqdcs);

  const int NB = (N_NODES + EPB - 1) / EPB;   // 469

  // two message-passing layers; node kernel emits the NEXT stage's P
  for (int l = 0; l < 2; ++l) {
    edge_mfma_kernel<<<N_EDGES / EPB, 256, 0, stream>>>(
        Pbuf, rcp, era, cstart,
        e_w1 + (size_t)l * 258 * HDIM + 256 * HDIM,
        w2cs + (size_t)l * 4 * 4096, e_b2 + l * HDIM, agg, headp);
    node_mfma_kernel<<<NB, 256, 0, stream>>>(
        out, agg, cstart, cursor, headp,
        enccs + (size_t)l * 8 * 4096, enc_b + l * HDIM,
        wqdcs + (size_t)l * 4 * 4096, dec_b + l * HDIM,
        (l == 0) ? (w1cs + (size_t)9 * 4096) : cw1cs,
        (l == 0) ? (e_b1 + HDIM) : c_b1,
        Pbuf);
  }

  // coordinate head
  coord_mfma_kernel<<<N_EDGES / EPB, 256, 0, stream>>>(
      Pbuf, rcp, era, x, c_w1 + 256 * HDIM, cw2cs, c_b2, c_w3,
      out + (size_t)N_NODES * HDIM);
}